// Round 8
// baseline (401.167 us; speedup 1.0000x reference)
//
#include <hip/hip_runtime.h>

#define NN 10000
#define EE 160000

typedef __attribute__((ext_vector_type(8))) short bf16x8;
typedef __attribute__((ext_vector_type(4))) float f32x4;

__device__ __forceinline__ float b2f(unsigned short s) {
    union { unsigned u; float f; } v; v.u = ((unsigned)s) << 16; return v.f;
}
__device__ __forceinline__ short f2b(float f) {
    union { float f; unsigned u; } v; v.f = f;
    unsigned r = v.u + 0x7FFF + ((v.u >> 16) & 1);  // RNE
    return (short)(r >> 16);
}

// ---------------------------------------------------------------- CSR build
__global__ __launch_bounds__(256) void hist_kernel(const int* __restrict__ dst,
                                                   int* __restrict__ counts, int E) {
    int e = blockIdx.x * 256 + threadIdx.x;
    if (e < E) atomicAdd(&counts[dst[e]], 1);
}

// LDS-staged single-block scan
__global__ __launch_bounds__(256) void scan_kernel(const int* __restrict__ counts,
                                                   int* __restrict__ off,
                                                   int* __restrict__ cur, int n) {
    __shared__ int buf[NN];
    __shared__ int part[256];
    int tid = threadIdx.x;
    for (int j = tid; j < n; j += 256) buf[j] = counts[j];
    __syncthreads();
    int chunk = (n + 255) / 256;
    int lo = tid * chunk; if (lo > n) lo = n;
    int hi = lo + chunk;  if (hi > n) hi = n;
    int s = 0;
    for (int i = lo; i < hi; ++i) s += buf[i];
    part[tid] = s;
    __syncthreads();
    for (int o = 1; o < 256; o <<= 1) {
        int v = (tid >= o) ? part[tid - o] : 0;
        __syncthreads();
        part[tid] += v;
        __syncthreads();
    }
    int run = (tid == 0) ? 0 : part[tid - 1];
    for (int i = lo; i < hi; ++i) { int c = buf[i]; buf[i] = run; run += c; }
    __syncthreads();
    for (int j = tid; j < n; j += 256) { int v = buf[j]; off[j] = v; cur[j] = v; }
    if (tid == 255) off[n] = part[255];
}

// fill + layer-1 edge-extra fused
__global__ __launch_bounds__(256) void fill_extra(const int* __restrict__ src,
                                                  const int* __restrict__ dst,
                                                  int* __restrict__ cur,
                                                  const float* __restrict__ ef,
                                                  const float* __restrict__ vbuf,
                                                  int* __restrict__ ssrc,
                                                  float* __restrict__ extra, int E) {
    __shared__ float vs[256];
    vs[threadIdx.x] = vbuf[threadIdx.x];
    __syncthreads();
    int e = blockIdx.x * 256 + threadIdx.x;
    if (e >= E) return;
    int p = atomicAdd(&cur[dst[e]], 1);
    ssrc[p] = src[e];
    float a0 = 0.f, a1 = 0.f, a2 = 0.f, a3 = 0.f;
    const float4* e4 = (const float4*)(ef + (size_t)e * 64);
    #pragma unroll
    for (int c = 0; c < 16; ++c) {
        float4 x = e4[c];
        int b = c * 16;
        a0 += x.x * vs[b + 0] + x.y * vs[b + 4] + x.z * vs[b + 8] + x.w * vs[b + 12];
        a1 += x.x * vs[b + 1] + x.y * vs[b + 5] + x.z * vs[b + 9] + x.w * vs[b + 13];
        a2 += x.x * vs[b + 2] + x.y * vs[b + 6] + x.z * vs[b + 10] + x.w * vs[b + 14];
        a3 += x.x * vs[b + 3] + x.y * vs[b + 7] + x.z * vs[b + 11] + x.w * vs[b + 15];
    }
    float4 o; o.x = a0; o.y = a1; o.z = a2; o.w = a3;
    *(float4*)(extra + (size_t)p * 4) = o;
}

// --------------------------- one prep kernel, all branches wave-parallel
struct PrepParams {
    const float* tsrc[8];
    short* tdst[8];
    int tN[8];
    int tshift[8];
    int tcum4[9];
    const float* W[4]; const float* al[4]; const float* ar[4];
    short* Wc[4]; int Dl[4]; int base[4];
    const float* We1; const float* ae1; float* vbuf;
    const float* node_feats; short* xb;
    int* counts;
    int bWA, bV, bC, bZ;
};
__global__ __launch_bounds__(256) void prep_kernel(PrepParams P) {
    int blk = blockIdx.x, tid = threadIdx.x;
    if (blk < P.bWA) {
        int t = blk * 256 + tid;
        if (t >= P.tcum4[8]) return;
        int i = 0;
        #pragma unroll
        for (int j = 1; j < 8; ++j) i += (t >= P.tcum4[j]);
        int local = t - P.tcum4[i];
        int N = P.tN[i], sh = P.tshift[i];
        int k = local >> (sh - 2);
        int nq = local & ((N >> 2) - 1);
        float4 v = *(const float4*)(P.tsrc[i] + (size_t)k * N + nq * 4);
        short* d = P.tdst[i] + (size_t)nq * 4 * 128 + k;
        d[0] = f2b(v.x); d[128] = f2b(v.y); d[256] = f2b(v.z); d[384] = f2b(v.w);
    } else if (blk < P.bV) {
        int bl = blk - P.bWA;
        int l = bl >> 7, within = bl & 127;
        int wv = tid >> 6, ln = tid & 63;
        int wid = within * 4 + wv;
        int k = wid >> 2, h = wid & 3;
        int D = P.Dl[l];
        const float* w = P.W[l] + ((size_t)k * 4 + h) * D;
        const float* a = P.al[l] + (size_t)h * D;
        const float* r = P.ar[l] + (size_t)h * D;
        float sa, sr;
        if (D == 128) {
            float2 w2 = ((const float2*)w)[ln];
            float2 a2 = ((const float2*)a)[ln];
            float2 r2 = ((const float2*)r)[ln];
            sa = w2.x * a2.x + w2.y * a2.y;
            sr = w2.x * r2.x + w2.y * r2.y;
        } else {
            float4 w4 = ((const float4*)w)[ln];
            float4 a4 = ((const float4*)a)[ln];
            float4 r4 = ((const float4*)r)[ln];
            sa = w4.x * a4.x + w4.y * a4.y + w4.z * a4.z + w4.w * a4.w;
            sr = w4.x * r4.x + w4.y * r4.y + w4.z * r4.z + w4.w * r4.w;
        }
        #pragma unroll
        for (int o = 32; o; o >>= 1) { sa += __shfl_xor(sa, o); sr += __shfl_xor(sr, o); }
        if (ln == 0) {
            P.Wc[l][(size_t)(P.base[l] + h) * 128 + k]     = f2b(sa);
            P.Wc[l][(size_t)(P.base[l] + 4 + h) * 128 + k] = f2b(sr);
        }
    } else if (blk < P.bC) {
        int bl = blk - P.bV;
        int wv = tid >> 6, ln = tid & 63;
        int i = bl * 4 + wv;
        #pragma unroll
        for (int h = 0; h < 4; ++h) {
            const float* w = P.We1 + ((size_t)i * 4 + h) * 128;
            const float* a = P.ae1 + (size_t)h * 128;
            float2 w2 = ((const float2*)w)[ln];
            float2 a2 = ((const float2*)a)[ln];
            float s = w2.x * a2.x + w2.y * a2.y;
            #pragma unroll
            for (int o = 32; o; o >>= 1) s += __shfl_xor(s, o);
            if (ln == 0) P.vbuf[i * 4 + h] = s;
        }
    } else if (blk < P.bZ) {
        int t = (blk - P.bC) * 256 + tid;
        if (t < NN * 32) {
            float4 v = ((const float4*)P.node_feats)[t];
            uint2 pk;
            pk.x = (unsigned short)f2b(v.x) | ((unsigned)(unsigned short)f2b(v.y) << 16);
            pk.y = (unsigned short)f2b(v.z) | ((unsigned)(unsigned short)f2b(v.w) << 16);
            ((uint2*)P.xb)[t] = pk;
        }
    } else {
        int t = (blk - P.bZ) * 256 + tid;
        if (t < NN / 4) ((int4*)P.counts)[t] = make_int4(0, 0, 0, 0);
    }
}

// --------------------------------- fused GEMM: feat (bf16) + res (f32) + el/er
template <int D>
__global__ __launch_bounds__(256) void gemm_fused(const short* __restrict__ A,
                                                  const short* __restrict__ Bt,
                                                  short* __restrict__ featb,
                                                  float* __restrict__ y,
                                                  float* __restrict__ elr,
                                                  int M) {
    constexpr int HD = 4 * D;
    int wave = threadIdx.x >> 6, lane = threadIdx.x & 63;
    int m0 = blockIdx.y * 64;
    int n0 = blockIdx.x * 64 + wave * 16;
    int r = lane & 15, quad = lane >> 4;
    f32x4 acc[4] = {};
    const short* bp = Bt + (size_t)(n0 + r) * 128 + quad * 8;
    #pragma unroll
    for (int k0 = 0; k0 < 128; k0 += 32) {
        bf16x8 bfrag = *(const bf16x8*)(bp + k0);
        #pragma unroll
        for (int mt = 0; mt < 4; ++mt) {
            int gm = m0 + mt * 16 + r;
            bf16x8 afrag = {};
            if (gm < M) afrag = *(const bf16x8*)(A + (size_t)gm * 128 + k0 + quad * 8);
            acc[mt] = __builtin_amdgcn_mfma_f32_16x16x32_bf16(afrag, bfrag, acc[mt], 0, 0, 0);
        }
    }
    int col = n0 + r;
    #pragma unroll
    for (int mt = 0; mt < 4; ++mt) {
        #pragma unroll
        for (int rr = 0; rr < 4; ++rr) {
            int gm = m0 + mt * 16 + quad * 4 + rr;
            if (gm >= M) continue;
            float v = acc[mt][rr];
            if (col < HD)              featb[(size_t)gm * HD + col] = f2b(v);
            else if (col < HD + D)     y[(size_t)gm * D + (col - HD)] = v;
            else if (col < HD + D + 8) elr[(size_t)gm * 8 + (col - HD - D)] = v;
        }
    }
}

// ------------------------------------------------- gather helpers
__device__ __forceinline__ void accum8(float* a, uint4 v, float w) {
    a[0] += w * b2f((unsigned short)(v.x & 0xFFFF));
    a[1] += w * b2f((unsigned short)(v.x >> 16));
    a[2] += w * b2f((unsigned short)(v.y & 0xFFFF));
    a[3] += w * b2f((unsigned short)(v.y >> 16));
    a[4] += w * b2f((unsigned short)(v.z & 0xFFFF));
    a[5] += w * b2f((unsigned short)(v.z >> 16));
    a[6] += w * b2f((unsigned short)(v.w & 0xFFFF));
    a[7] += w * b2f((unsigned short)(v.w >> 16));
}

// NOTE: all __shfl calls are executed UNCONDITIONALLY by the full wave,
// then selected with scalar ternaries — ds_bpermute from a lane that is
// inactive under EXEC is undefined (R7 bug).
__device__ __forceinline__ float sel4(int ln, float s0, float s1, float s2, float s3) {
    return ln < 16 ? s0 : ln < 32 ? s1 : ln < 48 ? s2 : s3;
}

// quarter-select gather (D=128): head = ln/16; edges j=start, start+step, ...
__device__ __forceinline__ void gather_q(int cnt, int start, int step, int sidx,
                                         float e0, float e1, float e2, float e3,
                                         const short* __restrict__ base, int ln,
                                         float acc[8]) {
    int j = start;
    for (; j + 3 * step < cnt; j += 4 * step) {
        int jB = j + step, jC = j + 2 * step, jD = j + 3 * step;
        int s0 = __shfl(sidx, j), s1 = __shfl(sidx, jB);
        int s2 = __shfl(sidx, jC), s3 = __shfl(sidx, jD);
        uint4 v0 = *(const uint4*)(base + (size_t)s0 * 512);
        uint4 v1 = *(const uint4*)(base + (size_t)s1 * 512);
        uint4 v2 = *(const uint4*)(base + (size_t)s2 * 512);
        uint4 v3 = *(const uint4*)(base + (size_t)s3 * 512);
        float a00 = __shfl(e0, j),  a01 = __shfl(e1, j),  a02 = __shfl(e2, j),  a03 = __shfl(e3, j);
        float a10 = __shfl(e0, jB), a11 = __shfl(e1, jB), a12 = __shfl(e2, jB), a13 = __shfl(e3, jB);
        float a20 = __shfl(e0, jC), a21 = __shfl(e1, jC), a22 = __shfl(e2, jC), a23 = __shfl(e3, jC);
        float a30 = __shfl(e0, jD), a31 = __shfl(e1, jD), a32 = __shfl(e2, jD), a33 = __shfl(e3, jD);
        float w0 = sel4(ln, a00, a01, a02, a03);
        float w1 = sel4(ln, a10, a11, a12, a13);
        float w2 = sel4(ln, a20, a21, a22, a23);
        float w3 = sel4(ln, a30, a31, a32, a33);
        accum8(acc, v0, w0); accum8(acc, v1, w1);
        accum8(acc, v2, w2); accum8(acc, v3, w3);
    }
    for (; j < cnt; j += step) {
        int s0 = __shfl(sidx, j);
        uint4 v0 = *(const uint4*)(base + (size_t)s0 * 512);
        float a0 = __shfl(e0, j), a1 = __shfl(e1, j), a2 = __shfl(e2, j), a3 = __shfl(e3, j);
        float w0 = sel4(ln, a0, a1, a2, a3);
        accum8(acc, v0, w0);
    }
}

// pair-select gather (D=256 column-split): head = 2*half + (ln>=32)
__device__ __forceinline__ void gather_p(int cnt, int sidx, float eA, float eB,
                                         const short* __restrict__ base, int ln,
                                         float acc[8]) {
    int j = 0;
    for (; j + 4 <= cnt; j += 4) {
        int s0 = __shfl(sidx, j), s1 = __shfl(sidx, j + 1);
        int s2 = __shfl(sidx, j + 2), s3 = __shfl(sidx, j + 3);
        uint4 v0 = *(const uint4*)(base + (size_t)s0 * 1024);
        uint4 v1 = *(const uint4*)(base + (size_t)s1 * 1024);
        uint4 v2 = *(const uint4*)(base + (size_t)s2 * 1024);
        uint4 v3 = *(const uint4*)(base + (size_t)s3 * 1024);
        float a0A = __shfl(eA, j),     a0B = __shfl(eB, j);
        float a1A = __shfl(eA, j + 1), a1B = __shfl(eB, j + 1);
        float a2A = __shfl(eA, j + 2), a2B = __shfl(eB, j + 2);
        float a3A = __shfl(eA, j + 3), a3B = __shfl(eB, j + 3);
        float w0 = ln < 32 ? a0A : a0B;
        float w1 = ln < 32 ? a1A : a1B;
        float w2 = ln < 32 ? a2A : a2B;
        float w3 = ln < 32 ? a3A : a3B;
        accum8(acc, v0, w0); accum8(acc, v1, w1);
        accum8(acc, v2, w2); accum8(acc, v3, w3);
    }
    for (; j < cnt; ++j) {
        int s0 = __shfl(sidx, j);
        uint4 v0 = *(const uint4*)(base + (size_t)s0 * 1024);
        float aA = __shfl(eA, j), aB = __shfl(eB, j);
        float w0 = ln < 32 ? aA : aB;
        accum8(acc, v0, w0);
    }
}

// ---------------- D=128 layers: 2 waves/node, edge-split, LDS combine
template <bool HAS_EXTRA>
__global__ __launch_bounds__(256) void gat128(const short* __restrict__ featb,
                                              const float* __restrict__ elr,
                                              const float* __restrict__ extra,
                                              const int* __restrict__ ssrc,
                                              const int* __restrict__ off,
                                              const float* __restrict__ yres,
                                              short* __restrict__ ybf) {
    __shared__ float red[2][128];
    int wv = threadIdx.x >> 6, ln = threadIdx.x & 63;
    int slot = wv >> 1, half = wv & 1;
    int n = blockIdx.x * 2 + slot;
    int r0 = off[n], deg = off[n + 1] - r0;
    float4 erv = *(const float4*)(elr + (size_t)n * 8 + 4);
    float acc[8] = {0.f, 0.f, 0.f, 0.f, 0.f, 0.f, 0.f, 0.f};
    float sc0, sc1, sc2, sc3;

    auto logits = [&](int idx, float& a0, float& a1, float& a2, float& a3) {
        int s = ssrc[idx];
        float4 elv = *(const float4*)(elr + (size_t)s * 8);
        a0 = elv.x + erv.x; a1 = elv.y + erv.y; a2 = elv.z + erv.z; a3 = elv.w + erv.w;
        if (HAS_EXTRA) {
            float4 exv = *(const float4*)(extra + (size_t)idx * 4);
            a0 += exv.x; a1 += exv.y; a2 += exv.z; a3 += exv.w;
        }
        a0 = a0 > 0.f ? a0 : 0.2f * a0;
        a1 = a1 > 0.f ? a1 : 0.2f * a1;
        a2 = a2 > 0.f ? a2 : 0.2f * a2;
        a3 = a3 > 0.f ? a3 : 0.2f * a3;
        return s;
    };

    if (deg <= 64) {
        int sidx = 0;
        float a0 = -1e30f, a1 = -1e30f, a2 = -1e30f, a3 = -1e30f;
        if (ln < deg) sidx = logits(r0 + ln, a0, a1, a2, a3);
        float m0 = a0, m1 = a1, m2 = a2, m3 = a3;
        #pragma unroll
        for (int o = 32; o; o >>= 1) {
            m0 = fmaxf(m0, __shfl_xor(m0, o)); m1 = fmaxf(m1, __shfl_xor(m1, o));
            m2 = fmaxf(m2, __shfl_xor(m2, o)); m3 = fmaxf(m3, __shfl_xor(m3, o));
        }
        float e0 = 0.f, e1 = 0.f, e2 = 0.f, e3 = 0.f;
        if (ln < deg) {
            e0 = __expf(a0 - m0); e1 = __expf(a1 - m1);
            e2 = __expf(a2 - m2); e3 = __expf(a3 - m3);
        }
        float s0 = e0, s1 = e1, s2 = e2, s3 = e3;
        #pragma unroll
        for (int o = 32; o; o >>= 1) {
            s0 += __shfl_xor(s0, o); s1 += __shfl_xor(s1, o);
            s2 += __shfl_xor(s2, o); s3 += __shfl_xor(s3, o);
        }
        sc0 = 0.25f / (s0 + 1e-9f); sc1 = 0.25f / (s1 + 1e-9f);
        sc2 = 0.25f / (s2 + 1e-9f); sc3 = 0.25f / (s3 + 1e-9f);
        gather_q(deg, half, 2, sidx, e0, e1, e2, e3, featb + ln * 8, ln, acc);
    } else {
        float m0 = -1e30f, m1 = -1e30f, m2 = -1e30f, m3 = -1e30f;
        for (int base = 0; base < deg; base += 64) {
            float a0 = -1e30f, a1 = -1e30f, a2 = -1e30f, a3 = -1e30f;
            if (base + ln < deg) logits(r0 + base + ln, a0, a1, a2, a3);
            m0 = fmaxf(m0, a0); m1 = fmaxf(m1, a1); m2 = fmaxf(m2, a2); m3 = fmaxf(m3, a3);
        }
        #pragma unroll
        for (int o = 32; o; o >>= 1) {
            m0 = fmaxf(m0, __shfl_xor(m0, o)); m1 = fmaxf(m1, __shfl_xor(m1, o));
            m2 = fmaxf(m2, __shfl_xor(m2, o)); m3 = fmaxf(m3, __shfl_xor(m3, o));
        }
        float s0 = 0.f, s1 = 0.f, s2 = 0.f, s3 = 0.f;
        for (int base = 0; base < deg; base += 64) {
            float a0, a1, a2, a3;
            if (base + ln < deg) {
                logits(r0 + base + ln, a0, a1, a2, a3);
                s0 += __expf(a0 - m0); s1 += __expf(a1 - m1);
                s2 += __expf(a2 - m2); s3 += __expf(a3 - m3);
            }
        }
        #pragma unroll
        for (int o = 32; o; o >>= 1) {
            s0 += __shfl_xor(s0, o); s1 += __shfl_xor(s1, o);
            s2 += __shfl_xor(s2, o); s3 += __shfl_xor(s3, o);
        }
        sc0 = 0.25f / (s0 + 1e-9f); sc1 = 0.25f / (s1 + 1e-9f);
        sc2 = 0.25f / (s2 + 1e-9f); sc3 = 0.25f / (s3 + 1e-9f);
        for (int base = 0; base < deg; base += 64) {
            int sidx = 0;
            float e0 = 0.f, e1 = 0.f, e2 = 0.f, e3 = 0.f;
            if (base + ln < deg) {
                float a0, a1, a2, a3;
                sidx = logits(r0 + base + ln, a0, a1, a2, a3);
                e0 = __expf(a0 - m0); e1 = __expf(a1 - m1);
                e2 = __expf(a2 - m2); e3 = __expf(a3 - m3);
            }
            int cnt = deg - base; if (cnt > 64) cnt = 64;
            gather_q(cnt, half, 2, sidx, e0, e1, e2, e3, featb + ln * 8, ln, acc);
        }
    }

    // scale + head-reduce within wave
    float scl = sel4(ln, sc0, sc1, sc2, sc3);
    float t[8];
    #pragma unroll
    for (int i = 0; i < 8; ++i) {
        float v = acc[i] * scl;
        v += __shfl_xor(v, 16);
        v += __shfl_xor(v, 32);
        t[i] = v;
    }
    if (half == 1 && ln < 16) {
        #pragma unroll
        for (int i = 0; i < 8; ++i) red[slot][ln * 8 + i] = t[i];
    }
    __syncthreads();
    if (half == 0 && ln < 16) {
        int d0 = ln * 8;
        const float* yr = yres + (size_t)n * 128 + d0;
        float4 ya = *(const float4*)yr;
        float4 yb = *(const float4*)(yr + 4);
        float o[8];
        o[0] = fmaxf(ya.x + t[0] + red[slot][d0 + 0], 0.f);
        o[1] = fmaxf(ya.y + t[1] + red[slot][d0 + 1], 0.f);
        o[2] = fmaxf(ya.z + t[2] + red[slot][d0 + 2], 0.f);
        o[3] = fmaxf(ya.w + t[3] + red[slot][d0 + 3], 0.f);
        o[4] = fmaxf(yb.x + t[4] + red[slot][d0 + 4], 0.f);
        o[5] = fmaxf(yb.y + t[5] + red[slot][d0 + 5], 0.f);
        o[6] = fmaxf(yb.z + t[6] + red[slot][d0 + 6], 0.f);
        o[7] = fmaxf(yb.w + t[7] + red[slot][d0 + 7], 0.f);
        uint4 pk;
        pk.x = (unsigned short)f2b(o[0]) | ((unsigned)(unsigned short)f2b(o[1]) << 16);
        pk.y = (unsigned short)f2b(o[2]) | ((unsigned)(unsigned short)f2b(o[3]) << 16);
        pk.z = (unsigned short)f2b(o[4]) | ((unsigned)(unsigned short)f2b(o[5]) << 16);
        pk.w = (unsigned short)f2b(o[6]) | ((unsigned)(unsigned short)f2b(o[7]) << 16);
        *(uint4*)(ybf + (size_t)n * 128 + d0) = pk;
    }
}

// ---------------- D=256 layer 4: 2 waves/node, column-split, LDS combine
__global__ __launch_bounds__(256) void gat256(const short* __restrict__ featb,
                                              const float* __restrict__ elr,
                                              const int* __restrict__ ssrc,
                                              const int* __restrict__ off,
                                              const float* __restrict__ yres,
                                              float* __restrict__ yout) {
    __shared__ float red[2][256];
    int wv = threadIdx.x >> 6, ln = threadIdx.x & 63;
    int slot = wv >> 1, half = wv & 1;
    int n = blockIdx.x * 2 + slot;
    int r0 = off[n], deg = off[n + 1] - r0;
    float4 erv = *(const float4*)(elr + (size_t)n * 8 + 4);
    float acc[8] = {0.f, 0.f, 0.f, 0.f, 0.f, 0.f, 0.f, 0.f};
    float sc0, sc1, sc2, sc3;
    const short* base = featb + half * 512 + ln * 8;

    auto logits = [&](int idx, float& a0, float& a1, float& a2, float& a3) {
        int s = ssrc[idx];
        float4 elv = *(const float4*)(elr + (size_t)s * 8);
        a0 = elv.x + erv.x; a1 = elv.y + erv.y; a2 = elv.z + erv.z; a3 = elv.w + erv.w;
        a0 = a0 > 0.f ? a0 : 0.2f * a0;
        a1 = a1 > 0.f ? a1 : 0.2f * a1;
        a2 = a2 > 0.f ? a2 : 0.2f * a2;
        a3 = a3 > 0.f ? a3 : 0.2f * a3;
        return s;
    };

    if (deg <= 64) {
        int sidx = 0;
        float a0 = -1e30f, a1 = -1e30f, a2 = -1e30f, a3 = -1e30f;
        if (ln < deg) sidx = logits(r0 + ln, a0, a1, a2, a3);
        float m0 = a0, m1 = a1, m2 = a2, m3 = a3;
        #pragma unroll
        for (int o = 32; o; o >>= 1) {
            m0 = fmaxf(m0, __shfl_xor(m0, o)); m1 = fmaxf(m1, __shfl_xor(m1, o));
            m2 = fmaxf(m2, __shfl_xor(m2, o)); m3 = fmaxf(m3, __shfl_xor(m3, o));
        }
        float e0 = 0.f, e1 = 0.f, e2 = 0.f, e3 = 0.f;
        if (ln < deg) {
            e0 = __expf(a0 - m0); e1 = __expf(a1 - m1);
            e2 = __expf(a2 - m2); e3 = __expf(a3 - m3);
        }
        float s0 = e0, s1 = e1, s2 = e2, s3 = e3;
        #pragma unroll
        for (int o = 32; o; o >>= 1) {
            s0 += __shfl_xor(s0, o); s1 += __shfl_xor(s1, o);
            s2 += __shfl_xor(s2, o); s3 += __shfl_xor(s3, o);
        }
        sc0 = 0.25f / (s0 + 1e-9f); sc1 = 0.25f / (s1 + 1e-9f);
        sc2 = 0.25f / (s2 + 1e-9f); sc3 = 0.25f / (s3 + 1e-9f);
        float eA = half ? e2 : e0;
        float eB = half ? e3 : e1;
        gather_p(deg, sidx, eA, eB, base, ln, acc);
    } else {
        float m0 = -1e30f, m1 = -1e30f, m2 = -1e30f, m3 = -1e30f;
        for (int b = 0; b < deg; b += 64) {
            float a0 = -1e30f, a1 = -1e30f, a2 = -1e30f, a3 = -1e30f;
            if (b + ln < deg) logits(r0 + b + ln, a0, a1, a2, a3);
            m0 = fmaxf(m0, a0); m1 = fmaxf(m1, a1); m2 = fmaxf(m2, a2); m3 = fmaxf(m3, a3);
        }
        #pragma unroll
        for (int o = 32; o; o >>= 1) {
            m0 = fmaxf(m0, __shfl_xor(m0, o)); m1 = fmaxf(m1, __shfl_xor(m1, o));
            m2 = fmaxf(m2, __shfl_xor(m2, o)); m3 = fmaxf(m3, __shfl_xor(m3, o));
        }
        float s0 = 0.f, s1 = 0.f, s2 = 0.f, s3 = 0.f;
        for (int b = 0; b < deg; b += 64) {
            float a0, a1, a2, a3;
            if (b + ln < deg) {
                logits(r0 + b + ln, a0, a1, a2, a3);
                s0 += __expf(a0 - m0); s1 += __expf(a1 - m1);
                s2 += __expf(a2 - m2); s3 += __expf(a3 - m3);
            }
        }
        #pragma unroll
        for (int o = 32; o; o >>= 1) {
            s0 += __shfl_xor(s0, o); s1 += __shfl_xor(s1, o);
            s2 += __shfl_xor(s2, o); s3 += __shfl_xor(s3, o);
        }
        sc0 = 0.25f / (s0 + 1e-9f); sc1 = 0.25f / (s1 + 1e-9f);
        sc2 = 0.25f / (s2 + 1e-9f); sc3 = 0.25f / (s3 + 1e-9f);
        for (int b = 0; b < deg; b += 64) {
            int sidx = 0;
            float e0 = 0.f, e1 = 0.f, e2 = 0.f, e3 = 0.f;
            if (b + ln < deg) {
                float a0, a1, a2, a3;
                sidx = logits(r0 + b + ln, a0, a1, a2, a3);
                e0 = __expf(a0 - m0); e1 = __expf(a1 - m1);
                e2 = __expf(a2 - m2); e3 = __expf(a3 - m3);
            }
            int cnt = deg - b; if (cnt > 64) cnt = 64;
            float eA = half ? e2 : e0;
            float eB = half ? e3 : e1;
            gather_p(cnt, sidx, eA, eB, base, ln, acc);
        }
    }

    float sc = (ln < 32) ? (half ? sc2 : sc0) : (half ? sc3 : sc1);
    float t[8];
    #pragma unroll
    for (int i = 0; i < 8; ++i) {
        float v = acc[i] * sc;
        v += __shfl_xor(v, 32);
        t[i] = v;
    }
    if (half == 1 && ln < 32) {
        #pragma unroll
        for (int i = 0; i < 8; ++i) red[slot][ln * 8 + i] = t[i];
    }
    __syncthreads();
    if (half == 0 && ln < 32) {
        int d0 = ln * 8;
        const float* yr = yres + (size_t)n * 256 + d0;
        float4 ya = *(const float4*)yr;
        float4 yb = *(const float4*)(yr + 4);
        float4 oa, ob;
        oa.x = fmaxf(ya.x + t[0] + red[slot][d0 + 0], 0.f);
        oa.y = fmaxf(ya.y + t[1] + red[slot][d0 + 1], 0.f);
        oa.z = fmaxf(ya.z + t[2] + red[slot][d0 + 2], 0.f);
        oa.w = fmaxf(ya.w + t[3] + red[slot][d0 + 3], 0.f);
        ob.x = fmaxf(yb.x + t[4] + red[slot][d0 + 4], 0.f);
        ob.y = fmaxf(yb.y + t[5] + red[slot][d0 + 5], 0.f);
        ob.z = fmaxf(yb.z + t[6] + red[slot][d0 + 6], 0.f);
        ob.w = fmaxf(yb.w + t[7] + red[slot][d0 + 7], 0.f);
        *(float4*)(yout + (size_t)n * 256 + d0) = oa;
        *(float4*)(yout + (size_t)n * 256 + d0 + 4) = ob;
    }
}

// ---------------------------------------------------------------- host side
extern "C" void kernel_launch(void* const* d_in, const int* in_sizes, int n_in,
                              void* d_out, int out_size, void* d_ws, size_t ws_size,
                              hipStream_t stream) {
    const float* node_feats = (const float*)d_in[0];
    const float* edge_feats = (const float*)d_in[1];
    const int*   src        = (const int*)d_in[2];
    const int*   dst        = (const int*)d_in[3];
    const float* W1   = (const float*)d_in[4];
    const float* We1  = (const float*)d_in[5];
    const float* al1  = (const float*)d_in[6];
    const float* ar1  = (const float*)d_in[7];
    const float* ae1  = (const float*)d_in[8];
    const float* res1 = (const float*)d_in[9];
    const float* W2   = (const float*)d_in[10];
    const float* al2  = (const float*)d_in[11];
    const float* ar2  = (const float*)d_in[12];
    const float* res2 = (const float*)d_in[13];
    const float* W3   = (const float*)d_in[14];
    const float* al3  = (const float*)d_in[15];
    const float* ar3  = (const float*)d_in[16];
    const float* res3 = (const float*)d_in[17];
    const float* W4   = (const float*)d_in[18];
    const float* al4  = (const float*)d_in[19];
    const float* ar4  = (const float*)d_in[20];
    const float* res4 = (const float*)d_in[21];

    char* ws = (char*)d_ws;
    auto alloc = [&](size_t bytes) -> char* {
        char* p = ws;
        ws += (bytes + 255) & ~(size_t)255;
        return p;
    };
    int*   counts  = (int*)alloc((size_t)NN * 4);
    int*   offsets = (int*)alloc((size_t)(NN + 1) * 4);
    int*   cursor  = (int*)alloc((size_t)(NN + 1) * 4);
    int*   ssrc    = (int*)alloc((size_t)EE * 4);
    short* featb   = (short*)alloc((size_t)NN * 1024 * 2);
    float* xA      = (float*)alloc((size_t)NN * 128 * 4);
    short* xb      = (short*)alloc((size_t)NN * 128 * 2);
    float* elr     = (float*)alloc((size_t)NN * 8 * 4);
    float* extra   = (float*)alloc((size_t)EE * 4 * 4);
    float* vbuf    = (float*)alloc(1024);
    short* Wc1     = (short*)alloc((size_t)704 * 128 * 2);
    short* Wc2     = (short*)alloc((size_t)704 * 128 * 2);
    short* Wc3     = (short*)alloc((size_t)704 * 128 * 2);
    short* Wc4     = (short*)alloc((size_t)1344 * 128 * 2);

    PrepParams P;
    P.tsrc[0] = W1;   P.tdst[0] = Wc1;              P.tN[0] = 512;  P.tshift[0] = 9;
    P.tsrc[1] = W2;   P.tdst[1] = Wc2;              P.tN[1] = 512;  P.tshift[1] = 9;
    P.tsrc[2] = W3;   P.tdst[2] = Wc3;              P.tN[2] = 512;  P.tshift[2] = 9;
    P.tsrc[3] = W4;   P.tdst[3] = Wc4;              P.tN[3] = 1024; P.tshift[3] = 10;
    P.tsrc[4] = res1; P.tdst[4] = Wc1 + 512 * 128;  P.tN[4] = 128;  P.tshift[4] = 7;
    P.tsrc[5] = res2; P.tdst[5] = Wc2 + 512 * 128;  P.tN[5] = 128;  P.tshift[5] = 7;
    P.tsrc[6] = res3; P.tdst[6] = Wc3 + 512 * 128;  P.tN[6] = 128;  P.tshift[6] = 7;
    P.tsrc[7] = res4; P.tdst[7] = Wc4 + 1024 * 128; P.tN[7] = 256;  P.tshift[7] = 8;
    P.tcum4[0] = 0;
    for (int i = 0; i < 8; ++i) P.tcum4[i + 1] = P.tcum4[i] + P.tN[i] * 128 / 4;
    P.W[0] = W1; P.W[1] = W2; P.W[2] = W3; P.W[3] = W4;
    P.al[0] = al1; P.al[1] = al2; P.al[2] = al3; P.al[3] = al4;
    P.ar[0] = ar1; P.ar[1] = ar2; P.ar[2] = ar3; P.ar[3] = ar4;
    P.Wc[0] = Wc1; P.Wc[1] = Wc2; P.Wc[2] = Wc3; P.Wc[3] = Wc4;
    P.Dl[0] = 128; P.Dl[1] = 128; P.Dl[2] = 128; P.Dl[3] = 256;
    P.base[0] = 640; P.base[1] = 640; P.base[2] = 640; P.base[3] = 1280;
    P.We1 = We1; P.ae1 = ae1; P.vbuf = vbuf;
    P.node_feats = node_feats; P.xb = xb;
    P.counts = counts;
    P.bWA = (P.tcum4[8] + 255) / 256;
    P.bV  = P.bWA + 512;
    P.bC  = P.bV + 16;
    P.bZ  = P.bC + (NN * 32 + 255) / 256;
    int nblk = P.bZ + (NN / 4 + 255) / 256;
    prep_kernel<<<nblk, 256, 0, stream>>>(P);

    hist_kernel<<<(EE + 255) / 256, 256, 0, stream>>>(dst, counts, EE);
    scan_kernel<<<1, 256, 0, stream>>>(counts, offsets, cursor, NN);
    fill_extra<<<(EE + 255) / 256, 256, 0, stream>>>(src, dst, cursor, edge_feats,
                                                     vbuf, ssrc, extra, EE);

    float* out = (float*)d_out;
    dim3 g128(11, (NN + 63) / 64);
    dim3 g256(21, (NN + 63) / 64);
    int gs = NN / 2;   // 5000 blocks, 2 nodes x 2 waves each

    // ---- layer 1
    gemm_fused<128><<<g128, 256, 0, stream>>>(xb, Wc1, featb, xA, elr, NN);
    gat128<true><<<gs, 256, 0, stream>>>(featb, elr, extra, ssrc, offsets, xA, xb);
    // ---- layer 2
    gemm_fused<128><<<g128, 256, 0, stream>>>(xb, Wc2, featb, xA, elr, NN);
    gat128<false><<<gs, 256, 0, stream>>>(featb, elr, nullptr, ssrc, offsets, xA, xb);
    // ---- layer 3
    gemm_fused<128><<<g128, 256, 0, stream>>>(xb, Wc3, featb, xA, elr, NN);
    gat128<false><<<gs, 256, 0, stream>>>(featb, elr, nullptr, ssrc, offsets, xA, xb);
    // ---- layer 4
    gemm_fused<256><<<g256, 256, 0, stream>>>(xb, Wc4, featb, out, elr, NN);
    gat256<<<gs, 256, 0, stream>>>(featb, elr, ssrc, offsets, out, out);
}

// Round 9
// 378.372 us; speedup vs baseline: 1.0602x; 1.0602x over previous
//
#include <hip/hip_runtime.h>

#define NN 10000
#define EE 160000

typedef __attribute__((ext_vector_type(8))) short bf16x8;
typedef __attribute__((ext_vector_type(4))) float f32x4;
typedef __attribute__((ext_vector_type(2))) float f32x2;

__device__ __forceinline__ float b2f(unsigned short s) {
    union { unsigned u; float f; } v; v.u = ((unsigned)s) << 16; return v.f;
}
__device__ __forceinline__ short f2b(float f) {
    union { float f; unsigned u; } v; v.f = f;
    unsigned r = v.u + 0x7FFF + ((v.u >> 16) & 1);  // RNE
    return (short)(r >> 16);
}
// fp8 e4m3 (OCP) encode via HW converter; returns low byte
__device__ __forceinline__ unsigned char f2q(float f) {
    return (unsigned char)(__builtin_amdgcn_cvt_pk_fp8_f32(f, f, 0, false) & 0xFF);
}

// ---------------------------------------------------------------- CSR build
__global__ __launch_bounds__(256) void hist_kernel(const int* __restrict__ dst,
                                                   int* __restrict__ counts, int E) {
    int e = blockIdx.x * 256 + threadIdx.x;
    if (e < E) atomicAdd(&counts[dst[e]], 1);
}

// LDS-staged single-block scan
__global__ __launch_bounds__(256) void scan_kernel(const int* __restrict__ counts,
                                                   int* __restrict__ off,
                                                   int* __restrict__ cur, int n) {
    __shared__ int buf[NN];
    __shared__ int part[256];
    int tid = threadIdx.x;
    for (int j = tid; j < n; j += 256) buf[j] = counts[j];
    __syncthreads();
    int chunk = (n + 255) / 256;
    int lo = tid * chunk; if (lo > n) lo = n;
    int hi = lo + chunk;  if (hi > n) hi = n;
    int s = 0;
    for (int i = lo; i < hi; ++i) s += buf[i];
    part[tid] = s;
    __syncthreads();
    for (int o = 1; o < 256; o <<= 1) {
        int v = (tid >= o) ? part[tid - o] : 0;
        __syncthreads();
        part[tid] += v;
        __syncthreads();
    }
    int run = (tid == 0) ? 0 : part[tid - 1];
    for (int i = lo; i < hi; ++i) { int c = buf[i]; buf[i] = run; run += c; }
    __syncthreads();
    for (int j = tid; j < n; j += 256) { int v = buf[j]; off[j] = v; cur[j] = v; }
    if (tid == 255) off[n] = part[255];
}

// fill + layer-1 edge-extra fused
__global__ __launch_bounds__(256) void fill_extra(const int* __restrict__ src,
                                                  const int* __restrict__ dst,
                                                  int* __restrict__ cur,
                                                  const float* __restrict__ ef,
                                                  const float* __restrict__ vbuf,
                                                  int* __restrict__ ssrc,
                                                  float* __restrict__ extra, int E) {
    __shared__ float vs[256];
    vs[threadIdx.x] = vbuf[threadIdx.x];
    __syncthreads();
    int e = blockIdx.x * 256 + threadIdx.x;
    if (e >= E) return;
    int p = atomicAdd(&cur[dst[e]], 1);
    ssrc[p] = src[e];
    float a0 = 0.f, a1 = 0.f, a2 = 0.f, a3 = 0.f;
    const float4* e4 = (const float4*)(ef + (size_t)e * 64);
    #pragma unroll
    for (int c = 0; c < 16; ++c) {
        float4 x = e4[c];
        int b = c * 16;
        a0 += x.x * vs[b + 0] + x.y * vs[b + 4] + x.z * vs[b + 8] + x.w * vs[b + 12];
        a1 += x.x * vs[b + 1] + x.y * vs[b + 5] + x.z * vs[b + 9] + x.w * vs[b + 13];
        a2 += x.x * vs[b + 2] + x.y * vs[b + 6] + x.z * vs[b + 10] + x.w * vs[b + 14];
        a3 += x.x * vs[b + 3] + x.y * vs[b + 7] + x.z * vs[b + 11] + x.w * vs[b + 15];
    }
    float4 o; o.x = a0; o.y = a1; o.z = a2; o.w = a3;
    *(float4*)(extra + (size_t)p * 4) = o;
}

// --------------------------- one prep kernel, all branches wave-parallel
struct PrepParams {
    const float* tsrc[8];
    short* tdst[8];
    int tN[8];
    int tshift[8];
    int tcum4[9];
    const float* W[4]; const float* al[4]; const float* ar[4];
    short* Wc[4]; int Dl[4]; int base[4];
    const float* We1; const float* ae1; float* vbuf;
    const float* node_feats; short* xb;
    int* counts;
    int bWA, bV, bC, bZ;
};
__global__ __launch_bounds__(256) void prep_kernel(PrepParams P) {
    int blk = blockIdx.x, tid = threadIdx.x;
    if (blk < P.bWA) {
        int t = blk * 256 + tid;
        if (t >= P.tcum4[8]) return;
        int i = 0;
        #pragma unroll
        for (int j = 1; j < 8; ++j) i += (t >= P.tcum4[j]);
        int local = t - P.tcum4[i];
        int N = P.tN[i], sh = P.tshift[i];
        int k = local >> (sh - 2);
        int nq = local & ((N >> 2) - 1);
        float4 v = *(const float4*)(P.tsrc[i] + (size_t)k * N + nq * 4);
        short* d = P.tdst[i] + (size_t)nq * 4 * 128 + k;
        d[0] = f2b(v.x); d[128] = f2b(v.y); d[256] = f2b(v.z); d[384] = f2b(v.w);
    } else if (blk < P.bV) {
        int bl = blk - P.bWA;
        int l = bl >> 7, within = bl & 127;
        int wv = tid >> 6, ln = tid & 63;
        int wid = within * 4 + wv;
        int k = wid >> 2, h = wid & 3;
        int D = P.Dl[l];
        const float* w = P.W[l] + ((size_t)k * 4 + h) * D;
        const float* a = P.al[l] + (size_t)h * D;
        const float* r = P.ar[l] + (size_t)h * D;
        float sa, sr;
        if (D == 128) {
            float2 w2 = ((const float2*)w)[ln];
            float2 a2 = ((const float2*)a)[ln];
            float2 r2 = ((const float2*)r)[ln];
            sa = w2.x * a2.x + w2.y * a2.y;
            sr = w2.x * r2.x + w2.y * r2.y;
        } else {
            float4 w4 = ((const float4*)w)[ln];
            float4 a4 = ((const float4*)a)[ln];
            float4 r4 = ((const float4*)r)[ln];
            sa = w4.x * a4.x + w4.y * a4.y + w4.z * a4.z + w4.w * a4.w;
            sr = w4.x * r4.x + w4.y * r4.y + w4.z * r4.z + w4.w * r4.w;
        }
        #pragma unroll
        for (int o = 32; o; o >>= 1) { sa += __shfl_xor(sa, o); sr += __shfl_xor(sr, o); }
        if (ln == 0) {
            P.Wc[l][(size_t)(P.base[l] + h) * 128 + k]     = f2b(sa);
            P.Wc[l][(size_t)(P.base[l] + 4 + h) * 128 + k] = f2b(sr);
        }
    } else if (blk < P.bC) {
        int bl = blk - P.bV;
        int wv = tid >> 6, ln = tid & 63;
        int i = bl * 4 + wv;
        #pragma unroll
        for (int h = 0; h < 4; ++h) {
            const float* w = P.We1 + ((size_t)i * 4 + h) * 128;
            const float* a = P.ae1 + (size_t)h * 128;
            float2 w2 = ((const float2*)w)[ln];
            float2 a2 = ((const float2*)a)[ln];
            float s = w2.x * a2.x + w2.y * a2.y;
            #pragma unroll
            for (int o = 32; o; o >>= 1) s += __shfl_xor(s, o);
            if (ln == 0) P.vbuf[i * 4 + h] = s;
        }
    } else if (blk < P.bZ) {
        int t = (blk - P.bC) * 256 + tid;
        if (t < NN * 32) {
            float4 v = ((const float4*)P.node_feats)[t];
            uint2 pk;
            pk.x = (unsigned short)f2b(v.x) | ((unsigned)(unsigned short)f2b(v.y) << 16);
            pk.y = (unsigned short)f2b(v.z) | ((unsigned)(unsigned short)f2b(v.w) << 16);
            ((uint2*)P.xb)[t] = pk;
        }
    } else {
        int t = (blk - P.bZ) * 256 + tid;
        if (t < NN / 4) ((int4*)P.counts)[t] = make_int4(0, 0, 0, 0);
    }
}

// ---------------- fused GEMM: feat (fp8 e4m3) + res (f32) + el/er (f32)
template <int D>
__global__ __launch_bounds__(256) void gemm_fused(const short* __restrict__ A,
                                                  const short* __restrict__ Bt,
                                                  unsigned char* __restrict__ featq,
                                                  float* __restrict__ y,
                                                  float* __restrict__ elr,
                                                  int M) {
    constexpr int HD = 4 * D;
    int wave = threadIdx.x >> 6, lane = threadIdx.x & 63;
    int m0 = blockIdx.y * 64;
    int n0 = blockIdx.x * 64 + wave * 16;
    int r = lane & 15, quad = lane >> 4;
    f32x4 acc[4] = {};
    const short* bp = Bt + (size_t)(n0 + r) * 128 + quad * 8;
    #pragma unroll
    for (int k0 = 0; k0 < 128; k0 += 32) {
        bf16x8 bfrag = *(const bf16x8*)(bp + k0);
        #pragma unroll
        for (int mt = 0; mt < 4; ++mt) {
            int gm = m0 + mt * 16 + r;
            bf16x8 afrag = {};
            if (gm < M) afrag = *(const bf16x8*)(A + (size_t)gm * 128 + k0 + quad * 8);
            acc[mt] = __builtin_amdgcn_mfma_f32_16x16x32_bf16(afrag, bfrag, acc[mt], 0, 0, 0);
        }
    }
    int col = n0 + r;
    #pragma unroll
    for (int mt = 0; mt < 4; ++mt) {
        #pragma unroll
        for (int rr = 0; rr < 4; ++rr) {
            int gm = m0 + mt * 16 + quad * 4 + rr;
            if (gm >= M) continue;
            float v = acc[mt][rr];
            if (col < HD)              featq[(size_t)gm * HD + col] = f2q(v);
            else if (col < HD + D)     y[(size_t)gm * D + (col - HD)] = v;
            else if (col < HD + D + 8) elr[(size_t)gm * 8 + (col - HD - D)] = v;
        }
    }
}

// ------------------------------------------------- gather helpers (fp8)
__device__ __forceinline__ void accum8q(float* a, uint2 v, float w) {
    f32x2 p0 = __builtin_amdgcn_cvt_pk_f32_fp8(v.x, false);
    f32x2 p1 = __builtin_amdgcn_cvt_pk_f32_fp8(v.x, true);
    f32x2 p2 = __builtin_amdgcn_cvt_pk_f32_fp8(v.y, false);
    f32x2 p3 = __builtin_amdgcn_cvt_pk_f32_fp8(v.y, true);
    a[0] += w * p0.x; a[1] += w * p0.y;
    a[2] += w * p1.x; a[3] += w * p1.y;
    a[4] += w * p2.x; a[5] += w * p2.y;
    a[6] += w * p3.x; a[7] += w * p3.y;
}

// NOTE: all __shfl calls executed UNCONDITIONALLY by the full wave, then
// selected with scalar ternaries — ds_bpermute from an EXEC-inactive lane
// is undefined (R7 bug).
__device__ __forceinline__ float sel4(int ln, float s0, float s1, float s2, float s3) {
    return ln < 16 ? s0 : ln < 32 ? s1 : ln < 48 ? s2 : s3;
}

// quarter-select gather (D=128): head = ln/16; row = 512 B; 8 B/lane
__device__ __forceinline__ void gather_q(int cnt, int start, int step, int sidx,
                                         float e0, float e1, float e2, float e3,
                                         const unsigned char* __restrict__ base, int ln,
                                         float acc[8]) {
    int j = start;
    for (; j + 3 * step < cnt; j += 4 * step) {
        int jB = j + step, jC = j + 2 * step, jD = j + 3 * step;
        int s0 = __shfl(sidx, j), s1 = __shfl(sidx, jB);
        int s2 = __shfl(sidx, jC), s3 = __shfl(sidx, jD);
        uint2 v0 = *(const uint2*)(base + (size_t)s0 * 512);
        uint2 v1 = *(const uint2*)(base + (size_t)s1 * 512);
        uint2 v2 = *(const uint2*)(base + (size_t)s2 * 512);
        uint2 v3 = *(const uint2*)(base + (size_t)s3 * 512);
        float a00 = __shfl(e0, j),  a01 = __shfl(e1, j),  a02 = __shfl(e2, j),  a03 = __shfl(e3, j);
        float a10 = __shfl(e0, jB), a11 = __shfl(e1, jB), a12 = __shfl(e2, jB), a13 = __shfl(e3, jB);
        float a20 = __shfl(e0, jC), a21 = __shfl(e1, jC), a22 = __shfl(e2, jC), a23 = __shfl(e3, jC);
        float a30 = __shfl(e0, jD), a31 = __shfl(e1, jD), a32 = __shfl(e2, jD), a33 = __shfl(e3, jD);
        float w0 = sel4(ln, a00, a01, a02, a03);
        float w1 = sel4(ln, a10, a11, a12, a13);
        float w2 = sel4(ln, a20, a21, a22, a23);
        float w3 = sel4(ln, a30, a31, a32, a33);
        accum8q(acc, v0, w0); accum8q(acc, v1, w1);
        accum8q(acc, v2, w2); accum8q(acc, v3, w3);
    }
    for (; j < cnt; j += step) {
        int s0 = __shfl(sidx, j);
        uint2 v0 = *(const uint2*)(base + (size_t)s0 * 512);
        float a0 = __shfl(e0, j), a1 = __shfl(e1, j), a2 = __shfl(e2, j), a3 = __shfl(e3, j);
        float w0 = sel4(ln, a0, a1, a2, a3);
        accum8q(acc, v0, w0);
    }
}

// pair-select gather (D=256 column-split): row = 1024 B; 8 B/lane
__device__ __forceinline__ void gather_p(int cnt, int sidx, float eA, float eB,
                                         const unsigned char* __restrict__ base, int ln,
                                         float acc[8]) {
    int j = 0;
    for (; j + 4 <= cnt; j += 4) {
        int s0 = __shfl(sidx, j), s1 = __shfl(sidx, j + 1);
        int s2 = __shfl(sidx, j + 2), s3 = __shfl(sidx, j + 3);
        uint2 v0 = *(const uint2*)(base + (size_t)s0 * 1024);
        uint2 v1 = *(const uint2*)(base + (size_t)s1 * 1024);
        uint2 v2 = *(const uint2*)(base + (size_t)s2 * 1024);
        uint2 v3 = *(const uint2*)(base + (size_t)s3 * 1024);
        float a0A = __shfl(eA, j),     a0B = __shfl(eB, j);
        float a1A = __shfl(eA, j + 1), a1B = __shfl(eB, j + 1);
        float a2A = __shfl(eA, j + 2), a2B = __shfl(eB, j + 2);
        float a3A = __shfl(eA, j + 3), a3B = __shfl(eB, j + 3);
        float w0 = ln < 32 ? a0A : a0B;
        float w1 = ln < 32 ? a1A : a1B;
        float w2 = ln < 32 ? a2A : a2B;
        float w3 = ln < 32 ? a3A : a3B;
        accum8q(acc, v0, w0); accum8q(acc, v1, w1);
        accum8q(acc, v2, w2); accum8q(acc, v3, w3);
    }
    for (; j < cnt; ++j) {
        int s0 = __shfl(sidx, j);
        uint2 v0 = *(const uint2*)(base + (size_t)s0 * 1024);
        float aA = __shfl(eA, j), aB = __shfl(eB, j);
        float w0 = ln < 32 ? aA : aB;
        accum8q(acc, v0, w0);
    }
}

// ---------------- D=128 layers: 2 waves/node, edge-split, LDS combine
template <bool HAS_EXTRA>
__global__ __launch_bounds__(256) void gat128(const unsigned char* __restrict__ featq,
                                              const float* __restrict__ elr,
                                              const float* __restrict__ extra,
                                              const int* __restrict__ ssrc,
                                              const int* __restrict__ off,
                                              const float* __restrict__ yres,
                                              short* __restrict__ ybf) {
    __shared__ float red[2][128];
    int wv = threadIdx.x >> 6, ln = threadIdx.x & 63;
    int slot = wv >> 1, half = wv & 1;
    int n = blockIdx.x * 2 + slot;
    int r0 = off[n], deg = off[n + 1] - r0;
    float4 erv = *(const float4*)(elr + (size_t)n * 8 + 4);
    float acc[8] = {0.f, 0.f, 0.f, 0.f, 0.f, 0.f, 0.f, 0.f};
    float sc0, sc1, sc2, sc3;

    auto logits = [&](int idx, float& a0, float& a1, float& a2, float& a3) {
        int s = ssrc[idx];
        float4 elv = *(const float4*)(elr + (size_t)s * 8);
        a0 = elv.x + erv.x; a1 = elv.y + erv.y; a2 = elv.z + erv.z; a3 = elv.w + erv.w;
        if (HAS_EXTRA) {
            float4 exv = *(const float4*)(extra + (size_t)idx * 4);
            a0 += exv.x; a1 += exv.y; a2 += exv.z; a3 += exv.w;
        }
        a0 = a0 > 0.f ? a0 : 0.2f * a0;
        a1 = a1 > 0.f ? a1 : 0.2f * a1;
        a2 = a2 > 0.f ? a2 : 0.2f * a2;
        a3 = a3 > 0.f ? a3 : 0.2f * a3;
        return s;
    };

    if (deg <= 64) {
        int sidx = 0;
        float a0 = -1e30f, a1 = -1e30f, a2 = -1e30f, a3 = -1e30f;
        if (ln < deg) sidx = logits(r0 + ln, a0, a1, a2, a3);
        float m0 = a0, m1 = a1, m2 = a2, m3 = a3;
        #pragma unroll
        for (int o = 32; o; o >>= 1) {
            m0 = fmaxf(m0, __shfl_xor(m0, o)); m1 = fmaxf(m1, __shfl_xor(m1, o));
            m2 = fmaxf(m2, __shfl_xor(m2, o)); m3 = fmaxf(m3, __shfl_xor(m3, o));
        }
        float e0 = 0.f, e1 = 0.f, e2 = 0.f, e3 = 0.f;
        if (ln < deg) {
            e0 = __expf(a0 - m0); e1 = __expf(a1 - m1);
            e2 = __expf(a2 - m2); e3 = __expf(a3 - m3);
        }
        float s0 = e0, s1 = e1, s2 = e2, s3 = e3;
        #pragma unroll
        for (int o = 32; o; o >>= 1) {
            s0 += __shfl_xor(s0, o); s1 += __shfl_xor(s1, o);
            s2 += __shfl_xor(s2, o); s3 += __shfl_xor(s3, o);
        }
        sc0 = 0.25f / (s0 + 1e-9f); sc1 = 0.25f / (s1 + 1e-9f);
        sc2 = 0.25f / (s2 + 1e-9f); sc3 = 0.25f / (s3 + 1e-9f);
        gather_q(deg, half, 2, sidx, e0, e1, e2, e3, featq + ln * 8, ln, acc);
    } else {
        float m0 = -1e30f, m1 = -1e30f, m2 = -1e30f, m3 = -1e30f;
        for (int base = 0; base < deg; base += 64) {
            float a0 = -1e30f, a1 = -1e30f, a2 = -1e30f, a3 = -1e30f;
            if (base + ln < deg) logits(r0 + base + ln, a0, a1, a2, a3);
            m0 = fmaxf(m0, a0); m1 = fmaxf(m1, a1); m2 = fmaxf(m2, a2); m3 = fmaxf(m3, a3);
        }
        #pragma unroll
        for (int o = 32; o; o >>= 1) {
            m0 = fmaxf(m0, __shfl_xor(m0, o)); m1 = fmaxf(m1, __shfl_xor(m1, o));
            m2 = fmaxf(m2, __shfl_xor(m2, o)); m3 = fmaxf(m3, __shfl_xor(m3, o));
        }
        float s0 = 0.f, s1 = 0.f, s2 = 0.f, s3 = 0.f;
        for (int base = 0; base < deg; base += 64) {
            float a0, a1, a2, a3;
            if (base + ln < deg) {
                logits(r0 + base + ln, a0, a1, a2, a3);
                s0 += __expf(a0 - m0); s1 += __expf(a1 - m1);
                s2 += __expf(a2 - m2); s3 += __expf(a3 - m3);
            }
        }
        #pragma unroll
        for (int o = 32; o; o >>= 1) {
            s0 += __shfl_xor(s0, o); s1 += __shfl_xor(s1, o);
            s2 += __shfl_xor(s2, o); s3 += __shfl_xor(s3, o);
        }
        sc0 = 0.25f / (s0 + 1e-9f); sc1 = 0.25f / (s1 + 1e-9f);
        sc2 = 0.25f / (s2 + 1e-9f); sc3 = 0.25f / (s3 + 1e-9f);
        for (int base = 0; base < deg; base += 64) {
            int sidx = 0;
            float e0 = 0.f, e1 = 0.f, e2 = 0.f, e3 = 0.f;
            if (base + ln < deg) {
                float a0, a1, a2, a3;
                sidx = logits(r0 + base + ln, a0, a1, a2, a3);
                e0 = __expf(a0 - m0); e1 = __expf(a1 - m1);
                e2 = __expf(a2 - m2); e3 = __expf(a3 - m3);
            }
            int cnt = deg - base; if (cnt > 64) cnt = 64;
            gather_q(cnt, half, 2, sidx, e0, e1, e2, e3, featq + ln * 8, ln, acc);
        }
    }

    // scale + head-reduce within wave
    float scl = sel4(ln, sc0, sc1, sc2, sc3);
    float t[8];
    #pragma unroll
    for (int i = 0; i < 8; ++i) {
        float v = acc[i] * scl;
        v += __shfl_xor(v, 16);
        v += __shfl_xor(v, 32);
        t[i] = v;
    }
    if (half == 1 && ln < 16) {
        #pragma unroll
        for (int i = 0; i < 8; ++i) red[slot][ln * 8 + i] = t[i];
    }
    __syncthreads();
    if (half == 0 && ln < 16) {
        int d0 = ln * 8;
        const float* yr = yres + (size_t)n * 128 + d0;
        float4 ya = *(const float4*)yr;
        float4 yb = *(const float4*)(yr + 4);
        float o[8];
        o[0] = fmaxf(ya.x + t[0] + red[slot][d0 + 0], 0.f);
        o[1] = fmaxf(ya.y + t[1] + red[slot][d0 + 1], 0.f);
        o[2] = fmaxf(ya.z + t[2] + red[slot][d0 + 2], 0.f);
        o[3] = fmaxf(ya.w + t[3] + red[slot][d0 + 3], 0.f);
        o[4] = fmaxf(yb.x + t[4] + red[slot][d0 + 4], 0.f);
        o[5] = fmaxf(yb.y + t[5] + red[slot][d0 + 5], 0.f);
        o[6] = fmaxf(yb.z + t[6] + red[slot][d0 + 6], 0.f);
        o[7] = fmaxf(yb.w + t[7] + red[slot][d0 + 7], 0.f);
        uint4 pk;
        pk.x = (unsigned short)f2b(o[0]) | ((unsigned)(unsigned short)f2b(o[1]) << 16);
        pk.y = (unsigned short)f2b(o[2]) | ((unsigned)(unsigned short)f2b(o[3]) << 16);
        pk.z = (unsigned short)f2b(o[4]) | ((unsigned)(unsigned short)f2b(o[5]) << 16);
        pk.w = (unsigned short)f2b(o[6]) | ((unsigned)(unsigned short)f2b(o[7]) << 16);
        *(uint4*)(ybf + (size_t)n * 128 + d0) = pk;
    }
}

// ---------------- D=256 layer 4: 2 waves/node, column-split, LDS combine
__global__ __launch_bounds__(256) void gat256(const unsigned char* __restrict__ featq,
                                              const float* __restrict__ elr,
                                              const int* __restrict__ ssrc,
                                              const int* __restrict__ off,
                                              const float* __restrict__ yres,
                                              float* __restrict__ yout) {
    __shared__ float red[2][256];
    int wv = threadIdx.x >> 6, ln = threadIdx.x & 63;
    int slot = wv >> 1, half = wv & 1;
    int n = blockIdx.x * 2 + slot;
    int r0 = off[n], deg = off[n + 1] - r0;
    float4 erv = *(const float4*)(elr + (size_t)n * 8 + 4);
    float acc[8] = {0.f, 0.f, 0.f, 0.f, 0.f, 0.f, 0.f, 0.f};
    float sc0, sc1, sc2, sc3;
    const unsigned char* base = featq + half * 512 + ln * 8;

    auto logits = [&](int idx, float& a0, float& a1, float& a2, float& a3) {
        int s = ssrc[idx];
        float4 elv = *(const float4*)(elr + (size_t)s * 8);
        a0 = elv.x + erv.x; a1 = elv.y + erv.y; a2 = elv.z + erv.z; a3 = elv.w + erv.w;
        a0 = a0 > 0.f ? a0 : 0.2f * a0;
        a1 = a1 > 0.f ? a1 : 0.2f * a1;
        a2 = a2 > 0.f ? a2 : 0.2f * a2;
        a3 = a3 > 0.f ? a3 : 0.2f * a3;
        return s;
    };

    if (deg <= 64) {
        int sidx = 0;
        float a0 = -1e30f, a1 = -1e30f, a2 = -1e30f, a3 = -1e30f;
        if (ln < deg) sidx = logits(r0 + ln, a0, a1, a2, a3);
        float m0 = a0, m1 = a1, m2 = a2, m3 = a3;
        #pragma unroll
        for (int o = 32; o; o >>= 1) {
            m0 = fmaxf(m0, __shfl_xor(m0, o)); m1 = fmaxf(m1, __shfl_xor(m1, o));
            m2 = fmaxf(m2, __shfl_xor(m2, o)); m3 = fmaxf(m3, __shfl_xor(m3, o));
        }
        float e0 = 0.f, e1 = 0.f, e2 = 0.f, e3 = 0.f;
        if (ln < deg) {
            e0 = __expf(a0 - m0); e1 = __expf(a1 - m1);
            e2 = __expf(a2 - m2); e3 = __expf(a3 - m3);
        }
        float s0 = e0, s1 = e1, s2 = e2, s3 = e3;
        #pragma unroll
        for (int o = 32; o; o >>= 1) {
            s0 += __shfl_xor(s0, o); s1 += __shfl_xor(s1, o);
            s2 += __shfl_xor(s2, o); s3 += __shfl_xor(s3, o);
        }
        sc0 = 0.25f / (s0 + 1e-9f); sc1 = 0.25f / (s1 + 1e-9f);
        sc2 = 0.25f / (s2 + 1e-9f); sc3 = 0.25f / (s3 + 1e-9f);
        float eA = half ? e2 : e0;
        float eB = half ? e3 : e1;
        gather_p(deg, sidx, eA, eB, base, ln, acc);
    } else {
        float m0 = -1e30f, m1 = -1e30f, m2 = -1e30f, m3 = -1e30f;
        for (int b = 0; b < deg; b += 64) {
            float a0 = -1e30f, a1 = -1e30f, a2 = -1e30f, a3 = -1e30f;
            if (b + ln < deg) logits(r0 + b + ln, a0, a1, a2, a3);
            m0 = fmaxf(m0, a0); m1 = fmaxf(m1, a1); m2 = fmaxf(m2, a2); m3 = fmaxf(m3, a3);
        }
        #pragma unroll
        for (int o = 32; o; o >>= 1) {
            m0 = fmaxf(m0, __shfl_xor(m0, o)); m1 = fmaxf(m1, __shfl_xor(m1, o));
            m2 = fmaxf(m2, __shfl_xor(m2, o)); m3 = fmaxf(m3, __shfl_xor(m3, o));
        }
        float s0 = 0.f, s1 = 0.f, s2 = 0.f, s3 = 0.f;
        for (int b = 0; b < deg; b += 64) {
            float a0, a1, a2, a3;
            if (b + ln < deg) {
                logits(r0 + b + ln, a0, a1, a2, a3);
                s0 += __expf(a0 - m0); s1 += __expf(a1 - m1);
                s2 += __expf(a2 - m2); s3 += __expf(a3 - m3);
            }
        }
        #pragma unroll
        for (int o = 32; o; o >>= 1) {
            s0 += __shfl_xor(s0, o); s1 += __shfl_xor(s1, o);
            s2 += __shfl_xor(s2, o); s3 += __shfl_xor(s3, o);
        }
        sc0 = 0.25f / (s0 + 1e-9f); sc1 = 0.25f / (s1 + 1e-9f);
        sc2 = 0.25f / (s2 + 1e-9f); sc3 = 0.25f / (s3 + 1e-9f);
        for (int b = 0; b < deg; b += 64) {
            int sidx = 0;
            float e0 = 0.f, e1 = 0.f, e2 = 0.f, e3 = 0.f;
            if (b + ln < deg) {
                float a0, a1, a2, a3;
                sidx = logits(r0 + b + ln, a0, a1, a2, a3);
                e0 = __expf(a0 - m0); e1 = __expf(a1 - m1);
                e2 = __expf(a2 - m2); e3 = __expf(a3 - m3);
            }
            int cnt = deg - b; if (cnt > 64) cnt = 64;
            float eA = half ? e2 : e0;
            float eB = half ? e3 : e1;
            gather_p(cnt, sidx, eA, eB, base, ln, acc);
        }
    }

    float sc = (ln < 32) ? (half ? sc2 : sc0) : (half ? sc3 : sc1);
    float t[8];
    #pragma unroll
    for (int i = 0; i < 8; ++i) {
        float v = acc[i] * sc;
        v += __shfl_xor(v, 32);
        t[i] = v;
    }
    if (half == 1 && ln < 32) {
        #pragma unroll
        for (int i = 0; i < 8; ++i) red[slot][ln * 8 + i] = t[i];
    }
    __syncthreads();
    if (half == 0 && ln < 32) {
        int d0 = ln * 8;
        const float* yr = yres + (size_t)n * 256 + d0;
        float4 ya = *(const float4*)yr;
        float4 yb = *(const float4*)(yr + 4);
        float4 oa, ob;
        oa.x = fmaxf(ya.x + t[0] + red[slot][d0 + 0], 0.f);
        oa.y = fmaxf(ya.y + t[1] + red[slot][d0 + 1], 0.f);
        oa.z = fmaxf(ya.z + t[2] + red[slot][d0 + 2], 0.f);
        oa.w = fmaxf(ya.w + t[3] + red[slot][d0 + 3], 0.f);
        ob.x = fmaxf(yb.x + t[4] + red[slot][d0 + 4], 0.f);
        ob.y = fmaxf(yb.y + t[5] + red[slot][d0 + 5], 0.f);
        ob.z = fmaxf(yb.z + t[6] + red[slot][d0 + 6], 0.f);
        ob.w = fmaxf(yb.w + t[7] + red[slot][d0 + 7], 0.f);
        *(float4*)(yout + (size_t)n * 256 + d0) = oa;
        *(float4*)(yout + (size_t)n * 256 + d0 + 4) = ob;
    }
}

// ---------------------------------------------------------------- host side
extern "C" void kernel_launch(void* const* d_in, const int* in_sizes, int n_in,
                              void* d_out, int out_size, void* d_ws, size_t ws_size,
                              hipStream_t stream) {
    const float* node_feats = (const float*)d_in[0];
    const float* edge_feats = (const float*)d_in[1];
    const int*   src        = (const int*)d_in[2];
    const int*   dst        = (const int*)d_in[3];
    const float* W1   = (const float*)d_in[4];
    const float* We1  = (const float*)d_in[5];
    const float* al1  = (const float*)d_in[6];
    const float* ar1  = (const float*)d_in[7];
    const float* ae1  = (const float*)d_in[8];
    const float* res1 = (const float*)d_in[9];
    const float* W2   = (const float*)d_in[10];
    const float* al2  = (const float*)d_in[11];
    const float* ar2  = (const float*)d_in[12];
    const float* res2 = (const float*)d_in[13];
    const float* W3   = (const float*)d_in[14];
    const float* al3  = (const float*)d_in[15];
    const float* ar3  = (const float*)d_in[16];
    const float* res3 = (const float*)d_in[17];
    const float* W4   = (const float*)d_in[18];
    const float* al4  = (const float*)d_in[19];
    const float* ar4  = (const float*)d_in[20];
    const float* res4 = (const float*)d_in[21];

    char* ws = (char*)d_ws;
    auto alloc = [&](size_t bytes) -> char* {
        char* p = ws;
        ws += (bytes + 255) & ~(size_t)255;
        return p;
    };
    int*   counts  = (int*)alloc((size_t)NN * 4);
    int*   offsets = (int*)alloc((size_t)(NN + 1) * 4);
    int*   cursor  = (int*)alloc((size_t)(NN + 1) * 4);
    int*   ssrc    = (int*)alloc((size_t)EE * 4);
    unsigned char* featq = (unsigned char*)alloc((size_t)NN * 1024);
    float* xA      = (float*)alloc((size_t)NN * 128 * 4);
    short* xb      = (short*)alloc((size_t)NN * 128 * 2);
    float* elr     = (float*)alloc((size_t)NN * 8 * 4);
    float* extra   = (float*)alloc((size_t)EE * 4 * 4);
    float* vbuf    = (float*)alloc(1024);
    short* Wc1     = (short*)alloc((size_t)704 * 128 * 2);
    short* Wc2     = (short*)alloc((size_t)704 * 128 * 2);
    short* Wc3     = (short*)alloc((size_t)704 * 128 * 2);
    short* Wc4     = (short*)alloc((size_t)1344 * 128 * 2);

    PrepParams P;
    P.tsrc[0] = W1;   P.tdst[0] = Wc1;              P.tN[0] = 512;  P.tshift[0] = 9;
    P.tsrc[1] = W2;   P.tdst[1] = Wc2;              P.tN[1] = 512;  P.tshift[1] = 9;
    P.tsrc[2] = W3;   P.tdst[2] = Wc3;              P.tN[2] = 512;  P.tshift[2] = 9;
    P.tsrc[3] = W4;   P.tdst[3] = Wc4;              P.tN[3] = 1024; P.tshift[3] = 10;
    P.tsrc[4] = res1; P.tdst[4] = Wc1 + 512 * 128;  P.tN[4] = 128;  P.tshift[4] = 7;
    P.tsrc[5] = res2; P.tdst[5] = Wc2 + 512 * 128;  P.tN[5] = 128;  P.tshift[5] = 7;
    P.tsrc[6] = res3; P.tdst[6] = Wc3 + 512 * 128;  P.tN[6] = 128;  P.tshift[6] = 7;
    P.tsrc[7] = res4; P.tdst[7] = Wc4 + 1024 * 128; P.tN[7] = 256;  P.tshift[7] = 8;
    P.tcum4[0] = 0;
    for (int i = 0; i < 8; ++i) P.tcum4[i + 1] = P.tcum4[i] + P.tN[i] * 128 / 4;
    P.W[0] = W1; P.W[1] = W2; P.W[2] = W3; P.W[3] = W4;
    P.al[0] = al1; P.al[1] = al2; P.al[2] = al3; P.al[3] = al4;
    P.ar[0] = ar1; P.ar[1] = ar2; P.ar[2] = ar3; P.ar[3] = ar4;
    P.Wc[0] = Wc1; P.Wc[1] = Wc2; P.Wc[2] = Wc3; P.Wc[3] = Wc4;
    P.Dl[0] = 128; P.Dl[1] = 128; P.Dl[2] = 128; P.Dl[3] = 256;
    P.base[0] = 640; P.base[1] = 640; P.base[2] = 640; P.base[3] = 1280;
    P.We1 = We1; P.ae1 = ae1; P.vbuf = vbuf;
    P.node_feats = node_feats; P.xb = xb;
    P.counts = counts;
    P.bWA = (P.tcum4[8] + 255) / 256;
    P.bV  = P.bWA + 512;
    P.bC  = P.bV + 16;
    P.bZ  = P.bC + (NN * 32 + 255) / 256;
    int nblk = P.bZ + (NN / 4 + 255) / 256;
    prep_kernel<<<nblk, 256, 0, stream>>>(P);

    hist_kernel<<<(EE + 255) / 256, 256, 0, stream>>>(dst, counts, EE);
    scan_kernel<<<1, 256, 0, stream>>>(counts, offsets, cursor, NN);
    fill_extra<<<(EE + 255) / 256, 256, 0, stream>>>(src, dst, cursor, edge_feats,
                                                     vbuf, ssrc, extra, EE);

    float* out = (float*)d_out;
    dim3 g128(11, (NN + 63) / 64);
    dim3 g256(21, (NN + 63) / 64);
    int gs = NN / 2;   // 5000 blocks, 2 nodes x 2 waves each

    // ---- layer 1
    gemm_fused<128><<<g128, 256, 0, stream>>>(xb, Wc1, featq, xA, elr, NN);
    gat128<true><<<gs, 256, 0, stream>>>(featq, elr, extra, ssrc, offsets, xA, xb);
    // ---- layer 2
    gemm_fused<128><<<g128, 256, 0, stream>>>(xb, Wc2, featq, xA, elr, NN);
    gat128<false><<<gs, 256, 0, stream>>>(featq, elr, nullptr, ssrc, offsets, xA, xb);
    // ---- layer 3
    gemm_fused<128><<<g128, 256, 0, stream>>>(xb, Wc3, featq, xA, elr, NN);
    gat128<false><<<gs, 256, 0, stream>>>(featq, elr, nullptr, ssrc, offsets, xA, xb);
    // ---- layer 4
    gemm_fused<256><<<g256, 256, 0, stream>>>(xb, Wc4, featq, out, elr, NN);
    gat256<<<gs, 256, 0, stream>>>(featq, elr, ssrc, offsets, out, out);
}

// Round 10
// 366.414 us; speedup vs baseline: 1.0948x; 1.0326x over previous
//
#include <hip/hip_runtime.h>

#define NN 10000
#define EE 160000

typedef __attribute__((ext_vector_type(8))) short bf16x8;
typedef __attribute__((ext_vector_type(4))) float f32x4;
typedef __attribute__((ext_vector_type(2))) float f32x2;

__device__ __forceinline__ float b2f(unsigned short s) {
    union { unsigned u; float f; } v; v.u = ((unsigned)s) << 16; return v.f;
}
__device__ __forceinline__ short f2b(float f) {
    union { float f; unsigned u; } v; v.f = f;
    unsigned r = v.u + 0x7FFF + ((v.u >> 16) & 1);  // RNE
    return (short)(r >> 16);
}
// fp8 e4m3 (OCP) encode via HW converter; returns low byte
__device__ __forceinline__ unsigned char f2q(float f) {
    return (unsigned char)(__builtin_amdgcn_cvt_pk_fp8_f32(f, f, 0, false) & 0xFF);
}

// ---------------------------------------------------------------- CSR build
__global__ __launch_bounds__(256) void hist_kernel(const int* __restrict__ dst,
                                                   int* __restrict__ counts, int E) {
    int e = blockIdx.x * 256 + threadIdx.x;
    if (e < E) atomicAdd(&counts[dst[e]], 1);
}

// LDS-staged single-block scan
__global__ __launch_bounds__(256) void scan_kernel(const int* __restrict__ counts,
                                                   int* __restrict__ off,
                                                   int* __restrict__ cur, int n) {
    __shared__ int buf[NN];
    __shared__ int part[256];
    int tid = threadIdx.x;
    for (int j = tid; j < n; j += 256) buf[j] = counts[j];
    __syncthreads();
    int chunk = (n + 255) / 256;
    int lo = tid * chunk; if (lo > n) lo = n;
    int hi = lo + chunk;  if (hi > n) hi = n;
    int s = 0;
    for (int i = lo; i < hi; ++i) s += buf[i];
    part[tid] = s;
    __syncthreads();
    for (int o = 1; o < 256; o <<= 1) {
        int v = (tid >= o) ? part[tid - o] : 0;
        __syncthreads();
        part[tid] += v;
        __syncthreads();
    }
    int run = (tid == 0) ? 0 : part[tid - 1];
    for (int i = lo; i < hi; ++i) { int c = buf[i]; buf[i] = run; run += c; }
    __syncthreads();
    for (int j = tid; j < n; j += 256) { int v = buf[j]; off[j] = v; cur[j] = v; }
    if (tid == 255) off[n] = part[255];
}

// fill + layer-1 edge-extra fused
__global__ __launch_bounds__(256) void fill_extra(const int* __restrict__ src,
                                                  const int* __restrict__ dst,
                                                  int* __restrict__ cur,
                                                  const float* __restrict__ ef,
                                                  const float* __restrict__ vbuf,
                                                  int* __restrict__ ssrc,
                                                  float* __restrict__ extra, int E) {
    __shared__ float vs[256];
    vs[threadIdx.x] = vbuf[threadIdx.x];
    __syncthreads();
    int e = blockIdx.x * 256 + threadIdx.x;
    if (e >= E) return;
    int p = atomicAdd(&cur[dst[e]], 1);
    ssrc[p] = src[e];
    float a0 = 0.f, a1 = 0.f, a2 = 0.f, a3 = 0.f;
    const float4* e4 = (const float4*)(ef + (size_t)e * 64);
    #pragma unroll
    for (int c = 0; c < 16; ++c) {
        float4 x = e4[c];
        int b = c * 16;
        a0 += x.x * vs[b + 0] + x.y * vs[b + 4] + x.z * vs[b + 8] + x.w * vs[b + 12];
        a1 += x.x * vs[b + 1] + x.y * vs[b + 5] + x.z * vs[b + 9] + x.w * vs[b + 13];
        a2 += x.x * vs[b + 2] + x.y * vs[b + 6] + x.z * vs[b + 10] + x.w * vs[b + 14];
        a3 += x.x * vs[b + 3] + x.y * vs[b + 7] + x.z * vs[b + 11] + x.w * vs[b + 15];
    }
    float4 o; o.x = a0; o.y = a1; o.z = a2; o.w = a3;
    *(float4*)(extra + (size_t)p * 4) = o;
}

// --------------------------- one prep kernel, all branches wave-parallel
struct PrepParams {
    const float* tsrc[8];
    short* tdst[8];
    int tN[8];
    int tshift[8];
    int tcum4[9];
    const float* W[4]; const float* al[4]; const float* ar[4];
    short* Wc[4]; int Dl[4]; int base[4];
    const float* We1; const float* ae1; float* vbuf;
    const float* node_feats; short* xb;
    int* counts;
    int bWA, bV, bC, bZ;
};
__global__ __launch_bounds__(256) void prep_kernel(PrepParams P) {
    int blk = blockIdx.x, tid = threadIdx.x;
    if (blk < P.bWA) {
        int t = blk * 256 + tid;
        if (t >= P.tcum4[8]) return;
        int i = 0;
        #pragma unroll
        for (int j = 1; j < 8; ++j) i += (t >= P.tcum4[j]);
        int local = t - P.tcum4[i];
        int N = P.tN[i], sh = P.tshift[i];
        int k = local >> (sh - 2);
        int nq = local & ((N >> 2) - 1);
        float4 v = *(const float4*)(P.tsrc[i] + (size_t)k * N + nq * 4);
        short* d = P.tdst[i] + (size_t)nq * 4 * 128 + k;
        d[0] = f2b(v.x); d[128] = f2b(v.y); d[256] = f2b(v.z); d[384] = f2b(v.w);
    } else if (blk < P.bV) {
        int bl = blk - P.bWA;
        int l = bl >> 7, within = bl & 127;
        int wv = tid >> 6, ln = tid & 63;
        int wid = within * 4 + wv;
        int k = wid >> 2, h = wid & 3;
        int D = P.Dl[l];
        const float* w = P.W[l] + ((size_t)k * 4 + h) * D;
        const float* a = P.al[l] + (size_t)h * D;
        const float* r = P.ar[l] + (size_t)h * D;
        float sa, sr;
        if (D == 128) {
            float2 w2 = ((const float2*)w)[ln];
            float2 a2 = ((const float2*)a)[ln];
            float2 r2 = ((const float2*)r)[ln];
            sa = w2.x * a2.x + w2.y * a2.y;
            sr = w2.x * r2.x + w2.y * r2.y;
        } else {
            float4 w4 = ((const float4*)w)[ln];
            float4 a4 = ((const float4*)a)[ln];
            float4 r4 = ((const float4*)r)[ln];
            sa = w4.x * a4.x + w4.y * a4.y + w4.z * a4.z + w4.w * a4.w;
            sr = w4.x * r4.x + w4.y * r4.y + w4.z * r4.z + w4.w * r4.w;
        }
        #pragma unroll
        for (int o = 32; o; o >>= 1) { sa += __shfl_xor(sa, o); sr += __shfl_xor(sr, o); }
        if (ln == 0) {
            P.Wc[l][(size_t)(P.base[l] + h) * 128 + k]     = f2b(sa);
            P.Wc[l][(size_t)(P.base[l] + 4 + h) * 128 + k] = f2b(sr);
        }
    } else if (blk < P.bC) {
        int bl = blk - P.bV;
        int wv = tid >> 6, ln = tid & 63;
        int i = bl * 4 + wv;
        #pragma unroll
        for (int h = 0; h < 4; ++h) {
            const float* w = P.We1 + ((size_t)i * 4 + h) * 128;
            const float* a = P.ae1 + (size_t)h * 128;
            float2 w2 = ((const float2*)w)[ln];
            float2 a2 = ((const float2*)a)[ln];
            float s = w2.x * a2.x + w2.y * a2.y;
            #pragma unroll
            for (int o = 32; o; o >>= 1) s += __shfl_xor(s, o);
            if (ln == 0) P.vbuf[i * 4 + h] = s;
        }
    } else if (blk < P.bZ) {
        int t = (blk - P.bC) * 256 + tid;
        if (t < NN * 32) {
            float4 v = ((const float4*)P.node_feats)[t];
            uint2 pk;
            pk.x = (unsigned short)f2b(v.x) | ((unsigned)(unsigned short)f2b(v.y) << 16);
            pk.y = (unsigned short)f2b(v.z) | ((unsigned)(unsigned short)f2b(v.w) << 16);
            ((uint2*)P.xb)[t] = pk;
        }
    } else {
        int t = (blk - P.bZ) * 256 + tid;
        if (t < NN / 4) ((int4*)P.counts)[t] = make_int4(0, 0, 0, 0);
    }
}

// ---------------- fused GEMM: feat (fp8 e4m3) + res (f32) + el/er (f32)
template <int D>
__global__ __launch_bounds__(256) void gemm_fused(const short* __restrict__ A,
                                                  const short* __restrict__ Bt,
                                                  unsigned char* __restrict__ featq,
                                                  float* __restrict__ y,
                                                  float* __restrict__ elr,
                                                  int M) {
    constexpr int HD = 4 * D;
    int wave = threadIdx.x >> 6, lane = threadIdx.x & 63;
    int m0 = blockIdx.y * 64;
    int n0 = blockIdx.x * 64 + wave * 16;
    int r = lane & 15, quad = lane >> 4;
    f32x4 acc[4] = {};
    const short* bp = Bt + (size_t)(n0 + r) * 128 + quad * 8;
    #pragma unroll
    for (int k0 = 0; k0 < 128; k0 += 32) {
        bf16x8 bfrag = *(const bf16x8*)(bp + k0);
        #pragma unroll
        for (int mt = 0; mt < 4; ++mt) {
            int gm = m0 + mt * 16 + r;
            bf16x8 afrag = {};
            if (gm < M) afrag = *(const bf16x8*)(A + (size_t)gm * 128 + k0 + quad * 8);
            acc[mt] = __builtin_amdgcn_mfma_f32_16x16x32_bf16(afrag, bfrag, acc[mt], 0, 0, 0);
        }
    }
    int col = n0 + r;
    #pragma unroll
    for (int mt = 0; mt < 4; ++mt) {
        #pragma unroll
        for (int rr = 0; rr < 4; ++rr) {
            int gm = m0 + mt * 16 + quad * 4 + rr;
            if (gm >= M) continue;
            float v = acc[mt][rr];
            if (col < HD)              featq[(size_t)gm * HD + col] = f2q(v);
            else if (col < HD + D)     y[(size_t)gm * D + (col - HD)] = v;
            else if (col < HD + D + 8) elr[(size_t)gm * 8 + (col - HD - D)] = v;
        }
    }
}

// ------------------------------------------------- gather helpers (fp8, 16/lane)
__device__ __forceinline__ void accum16q(float* a, uint4 v, float w) {
    f32x2 p;
    p = __builtin_amdgcn_cvt_pk_f32_fp8(v.x, false); a[0] += w * p.x; a[1] += w * p.y;
    p = __builtin_amdgcn_cvt_pk_f32_fp8(v.x, true);  a[2] += w * p.x; a[3] += w * p.y;
    p = __builtin_amdgcn_cvt_pk_f32_fp8(v.y, false); a[4] += w * p.x; a[5] += w * p.y;
    p = __builtin_amdgcn_cvt_pk_f32_fp8(v.y, true);  a[6] += w * p.x; a[7] += w * p.y;
    p = __builtin_amdgcn_cvt_pk_f32_fp8(v.z, false); a[8] += w * p.x; a[9] += w * p.y;
    p = __builtin_amdgcn_cvt_pk_f32_fp8(v.z, true);  a[10] += w * p.x; a[11] += w * p.y;
    p = __builtin_amdgcn_cvt_pk_f32_fp8(v.w, false); a[12] += w * p.x; a[13] += w * p.y;
    p = __builtin_amdgcn_cvt_pk_f32_fp8(v.w, true);  a[14] += w * p.x; a[15] += w * p.y;
}

// All __shfl executed by the FULL wave with uniform trip counts; invalid
// edges are clamped+zero-masked (never EXEC-masked) — R7 lesson.
__device__ __forceinline__ float hsel(int h, float s0, float s1, float s2, float s3) {
    return h == 0 ? s0 : h == 1 ? s1 : h == 2 ? s2 : s3;
}

// gat128 gather: lane group g=ln>>5 covers full 512B row; pair it -> edge 2*it+g
__device__ __forceinline__ void gather128(int T, int deg, int g, int h, int sidx,
                                          float e0, float e1, float e2, float e3,
                                          const unsigned char* __restrict__ basep,
                                          float acc[16]) {
    int it = 0;
    for (; it + 4 <= T; it += 4) {
        int j0 = 2 * it + g, j1 = j0 + 2, j2 = j0 + 4, j3 = j0 + 6;
        int c0 = j0 < deg ? j0 : deg - 1;
        int c1 = j1 < deg ? j1 : deg - 1;
        int c2 = j2 < deg ? j2 : deg - 1;
        int c3 = j3 < deg ? j3 : deg - 1;
        float m0 = j0 < deg ? 1.f : 0.f, m1 = j1 < deg ? 1.f : 0.f;
        float m2 = j2 < deg ? 1.f : 0.f, m3 = j3 < deg ? 1.f : 0.f;
        int s0 = __shfl(sidx, c0), s1 = __shfl(sidx, c1);
        int s2 = __shfl(sidx, c2), s3 = __shfl(sidx, c3);
        uint4 v0 = *(const uint4*)(basep + (size_t)s0 * 512);
        uint4 v1 = *(const uint4*)(basep + (size_t)s1 * 512);
        uint4 v2 = *(const uint4*)(basep + (size_t)s2 * 512);
        uint4 v3 = *(const uint4*)(basep + (size_t)s3 * 512);
        float w0 = hsel(h, __shfl(e0, c0), __shfl(e1, c0), __shfl(e2, c0), __shfl(e3, c0)) * m0;
        float w1 = hsel(h, __shfl(e0, c1), __shfl(e1, c1), __shfl(e2, c1), __shfl(e3, c1)) * m1;
        float w2 = hsel(h, __shfl(e0, c2), __shfl(e1, c2), __shfl(e2, c2), __shfl(e3, c2)) * m2;
        float w3 = hsel(h, __shfl(e0, c3), __shfl(e1, c3), __shfl(e2, c3), __shfl(e3, c3)) * m3;
        accum16q(acc, v0, w0); accum16q(acc, v1, w1);
        accum16q(acc, v2, w2); accum16q(acc, v3, w3);
    }
    for (; it < T; ++it) {
        int j0 = 2 * it + g;
        int c0 = j0 < deg ? j0 : deg - 1;
        float m0 = j0 < deg ? 1.f : 0.f;
        int s0 = __shfl(sidx, c0);
        uint4 v0 = *(const uint4*)(basep + (size_t)s0 * 512);
        float w0 = hsel(h, __shfl(e0, c0), __shfl(e1, c0), __shfl(e2, c0), __shfl(e3, c0)) * m0;
        accum16q(acc, v0, w0);
    }
}

// gat256 gather: whole wave covers full 1024B row; edge 2*it+half
__device__ __forceinline__ void gather256(int T, int deg, int half, int h, int sidx,
                                          float e0, float e1, float e2, float e3,
                                          const unsigned char* __restrict__ basep,
                                          float acc[16]) {
    int it = 0;
    for (; it + 4 <= T; it += 4) {
        int j0 = 2 * it + half, j1 = j0 + 2, j2 = j0 + 4, j3 = j0 + 6;
        int c0 = j0 < deg ? j0 : deg - 1;
        int c1 = j1 < deg ? j1 : deg - 1;
        int c2 = j2 < deg ? j2 : deg - 1;
        int c3 = j3 < deg ? j3 : deg - 1;
        float m0 = j0 < deg ? 1.f : 0.f, m1 = j1 < deg ? 1.f : 0.f;
        float m2 = j2 < deg ? 1.f : 0.f, m3 = j3 < deg ? 1.f : 0.f;
        int s0 = __shfl(sidx, c0), s1 = __shfl(sidx, c1);
        int s2 = __shfl(sidx, c2), s3 = __shfl(sidx, c3);
        uint4 v0 = *(const uint4*)(basep + (size_t)s0 * 1024);
        uint4 v1 = *(const uint4*)(basep + (size_t)s1 * 1024);
        uint4 v2 = *(const uint4*)(basep + (size_t)s2 * 1024);
        uint4 v3 = *(const uint4*)(basep + (size_t)s3 * 1024);
        float w0 = hsel(h, __shfl(e0, c0), __shfl(e1, c0), __shfl(e2, c0), __shfl(e3, c0)) * m0;
        float w1 = hsel(h, __shfl(e0, c1), __shfl(e1, c1), __shfl(e2, c1), __shfl(e3, c1)) * m1;
        float w2 = hsel(h, __shfl(e0, c2), __shfl(e1, c2), __shfl(e2, c2), __shfl(e3, c2)) * m2;
        float w3 = hsel(h, __shfl(e0, c3), __shfl(e1, c3), __shfl(e2, c3), __shfl(e3, c3)) * m3;
        accum16q(acc, v0, w0); accum16q(acc, v1, w1);
        accum16q(acc, v2, w2); accum16q(acc, v3, w3);
    }
    for (; it < T; ++it) {
        int j0 = 2 * it + half;
        int c0 = j0 < deg ? j0 : deg - 1;
        float m0 = j0 < deg ? 1.f : 0.f;
        int s0 = __shfl(sidx, c0);
        uint4 v0 = *(const uint4*)(basep + (size_t)s0 * 1024);
        float w0 = hsel(h, __shfl(e0, c0), __shfl(e1, c0), __shfl(e2, c0), __shfl(e3, c0)) * m0;
        accum16q(acc, v0, w0);
    }
}

// softmax over up to 64 logits held one-per-lane (deg<=64 fast path helpers)
#define WAVE_MAX4(m0,m1,m2,m3)                                              \
    _Pragma("unroll")                                                       \
    for (int o = 32; o; o >>= 1) {                                          \
        m0 = fmaxf(m0, __shfl_xor(m0, o)); m1 = fmaxf(m1, __shfl_xor(m1, o));\
        m2 = fmaxf(m2, __shfl_xor(m2, o)); m3 = fmaxf(m3, __shfl_xor(m3, o));\
    }
#define WAVE_SUM4(s0,s1,s2,s3)                                              \
    _Pragma("unroll")                                                       \
    for (int o = 32; o; o >>= 1) {                                          \
        s0 += __shfl_xor(s0, o); s1 += __shfl_xor(s1, o);                   \
        s2 += __shfl_xor(s2, o); s3 += __shfl_xor(s3, o);                   \
    }

// ---------------- D=128 layers: 1 wave per node, dual-edge lanes, no LDS
template <bool HAS_EXTRA>
__global__ __launch_bounds__(256) void gat128(const unsigned char* __restrict__ featq,
                                              const float* __restrict__ elr,
                                              const float* __restrict__ extra,
                                              const int* __restrict__ ssrc,
                                              const int* __restrict__ off,
                                              const float* __restrict__ yres,
                                              short* __restrict__ ybf) {
    int wv = threadIdx.x >> 6, ln = threadIdx.x & 63;
    int n = blockIdx.x * 4 + wv;
    int r0 = off[n], deg = off[n + 1] - r0;
    int g = ln >> 5, l5 = ln & 31;
    int h = l5 >> 3;
    float4 erv = *(const float4*)(elr + (size_t)n * 8 + 4);
    float acc[16];
    #pragma unroll
    for (int i = 0; i < 16; ++i) acc[i] = 0.f;
    float sc0, sc1, sc2, sc3;
    const unsigned char* basep = featq + l5 * 16;

    auto logits = [&](int idx, float& a0, float& a1, float& a2, float& a3) {
        int s = ssrc[idx];
        float4 elv = *(const float4*)(elr + (size_t)s * 8);
        a0 = elv.x + erv.x; a1 = elv.y + erv.y; a2 = elv.z + erv.z; a3 = elv.w + erv.w;
        if (HAS_EXTRA) {
            float4 exv = *(const float4*)(extra + (size_t)idx * 4);
            a0 += exv.x; a1 += exv.y; a2 += exv.z; a3 += exv.w;
        }
        a0 = a0 > 0.f ? a0 : 0.2f * a0;
        a1 = a1 > 0.f ? a1 : 0.2f * a1;
        a2 = a2 > 0.f ? a2 : 0.2f * a2;
        a3 = a3 > 0.f ? a3 : 0.2f * a3;
        return s;
    };

    if (deg <= 64) {
        int sidx = 0;
        float a0 = -1e30f, a1 = -1e30f, a2 = -1e30f, a3 = -1e30f;
        if (ln < deg) sidx = logits(r0 + ln, a0, a1, a2, a3);
        float m0 = a0, m1 = a1, m2 = a2, m3 = a3;
        WAVE_MAX4(m0, m1, m2, m3)
        float e0 = 0.f, e1 = 0.f, e2 = 0.f, e3 = 0.f;
        if (ln < deg) {
            e0 = __expf(a0 - m0); e1 = __expf(a1 - m1);
            e2 = __expf(a2 - m2); e3 = __expf(a3 - m3);
        }
        float s0 = e0, s1 = e1, s2 = e2, s3 = e3;
        WAVE_SUM4(s0, s1, s2, s3)
        sc0 = 0.25f / (s0 + 1e-9f); sc1 = 0.25f / (s1 + 1e-9f);
        sc2 = 0.25f / (s2 + 1e-9f); sc3 = 0.25f / (s3 + 1e-9f);
        gather128((deg + 1) >> 1, deg, g, h, sidx, e0, e1, e2, e3, basep, acc);
    } else {
        float m0 = -1e30f, m1 = -1e30f, m2 = -1e30f, m3 = -1e30f;
        for (int b = 0; b < deg; b += 64) {
            float a0 = -1e30f, a1 = -1e30f, a2 = -1e30f, a3 = -1e30f;
            if (b + ln < deg) logits(r0 + b + ln, a0, a1, a2, a3);
            m0 = fmaxf(m0, a0); m1 = fmaxf(m1, a1); m2 = fmaxf(m2, a2); m3 = fmaxf(m3, a3);
        }
        WAVE_MAX4(m0, m1, m2, m3)
        float s0 = 0.f, s1 = 0.f, s2 = 0.f, s3 = 0.f;
        for (int b = 0; b < deg; b += 64) {
            float a0, a1, a2, a3;
            if (b + ln < deg) {
                logits(r0 + b + ln, a0, a1, a2, a3);
                s0 += __expf(a0 - m0); s1 += __expf(a1 - m1);
                s2 += __expf(a2 - m2); s3 += __expf(a3 - m3);
            }
        }
        WAVE_SUM4(s0, s1, s2, s3)
        sc0 = 0.25f / (s0 + 1e-9f); sc1 = 0.25f / (s1 + 1e-9f);
        sc2 = 0.25f / (s2 + 1e-9f); sc3 = 0.25f / (s3 + 1e-9f);
        for (int b = 0; b < deg; b += 64) {
            int sidx = 0;
            float e0 = 0.f, e1 = 0.f, e2 = 0.f, e3 = 0.f;
            if (b + ln < deg) {
                float a0, a1, a2, a3;
                sidx = logits(r0 + b + ln, a0, a1, a2, a3);
                e0 = __expf(a0 - m0); e1 = __expf(a1 - m1);
                e2 = __expf(a2 - m2); e3 = __expf(a3 - m3);
            }
            int cnt = deg - b; if (cnt > 64) cnt = 64;
            gather128((cnt + 1) >> 1, cnt, g, h, sidx, e0, e1, e2, e3, basep, acc);
        }
    }

    // per-head scale, then group-sum (xor32) + head-mean (xor8, xor16)
    float scl = hsel(h, sc0, sc1, sc2, sc3);
    float t[16];
    #pragma unroll
    for (int i = 0; i < 16; ++i) {
        float v = acc[i] * scl;
        v += __shfl_xor(v, 32);
        v += __shfl_xor(v, 8);
        v += __shfl_xor(v, 16);
        t[i] = v;
    }
    if (ln < 8) {
        int d0 = ln * 16;
        const float* yr = yres + (size_t)n * 128 + d0;
        unsigned pk[8];
        #pragma unroll
        for (int q = 0; q < 8; ++q) {
            float ya = yr[2 * q], yb = yr[2 * q + 1];
            float o0 = fmaxf(ya + t[2 * q], 0.f);
            float o1 = fmaxf(yb + t[2 * q + 1], 0.f);
            pk[q] = (unsigned short)f2b(o0) | ((unsigned)(unsigned short)f2b(o1) << 16);
        }
        uint4 pa, pb;
        pa.x = pk[0]; pa.y = pk[1]; pa.z = pk[2]; pa.w = pk[3];
        pb.x = pk[4]; pb.y = pk[5]; pb.z = pk[6]; pb.w = pk[7];
        *(uint4*)(ybf + (size_t)n * 128 + d0) = pa;
        *(uint4*)(ybf + (size_t)n * 128 + d0 + 8) = pb;
    }
}

// ---------------- D=256 layer 4: 2 waves/node edge-split, full-row lanes
__global__ __launch_bounds__(256) void gat256(const unsigned char* __restrict__ featq,
                                              const float* __restrict__ elr,
                                              const int* __restrict__ ssrc,
                                              const int* __restrict__ off,
                                              const float* __restrict__ yres,
                                              float* __restrict__ yout) {
    __shared__ float red[2][256];
    int wv = threadIdx.x >> 6, ln = threadIdx.x & 63;
    int slot = wv >> 1, half = wv & 1;
    int n = blockIdx.x * 2 + slot;
    int r0 = off[n], deg = off[n + 1] - r0;
    int h = ln >> 4;
    float4 erv = *(const float4*)(elr + (size_t)n * 8 + 4);
    float acc[16];
    #pragma unroll
    for (int i = 0; i < 16; ++i) acc[i] = 0.f;
    float sc0, sc1, sc2, sc3;
    const unsigned char* basep = featq + ln * 16;

    auto logits = [&](int idx, float& a0, float& a1, float& a2, float& a3) {
        int s = ssrc[idx];
        float4 elv = *(const float4*)(elr + (size_t)s * 8);
        a0 = elv.x + erv.x; a1 = elv.y + erv.y; a2 = elv.z + erv.z; a3 = elv.w + erv.w;
        a0 = a0 > 0.f ? a0 : 0.2f * a0;
        a1 = a1 > 0.f ? a1 : 0.2f * a1;
        a2 = a2 > 0.f ? a2 : 0.2f * a2;
        a3 = a3 > 0.f ? a3 : 0.2f * a3;
        return s;
    };

    if (deg <= 64) {
        int sidx = 0;
        float a0 = -1e30f, a1 = -1e30f, a2 = -1e30f, a3 = -1e30f;
        if (ln < deg) sidx = logits(r0 + ln, a0, a1, a2, a3);
        float m0 = a0, m1 = a1, m2 = a2, m3 = a3;
        WAVE_MAX4(m0, m1, m2, m3)
        float e0 = 0.f, e1 = 0.f, e2 = 0.f, e3 = 0.f;
        if (ln < deg) {
            e0 = __expf(a0 - m0); e1 = __expf(a1 - m1);
            e2 = __expf(a2 - m2); e3 = __expf(a3 - m3);
        }
        float s0 = e0, s1 = e1, s2 = e2, s3 = e3;
        WAVE_SUM4(s0, s1, s2, s3)
        sc0 = 0.25f / (s0 + 1e-9f); sc1 = 0.25f / (s1 + 1e-9f);
        sc2 = 0.25f / (s2 + 1e-9f); sc3 = 0.25f / (s3 + 1e-9f);
        gather256((deg + 1) >> 1, deg, half, h, sidx, e0, e1, e2, e3, basep, acc);
    } else {
        float m0 = -1e30f, m1 = -1e30f, m2 = -1e30f, m3 = -1e30f;
        for (int b = 0; b < deg; b += 64) {
            float a0 = -1e30f, a1 = -1e30f, a2 = -1e30f, a3 = -1e30f;
            if (b + ln < deg) logits(r0 + b + ln, a0, a1, a2, a3);
            m0 = fmaxf(m0, a0); m1 = fmaxf(m1, a1); m2 = fmaxf(m2, a2); m3 = fmaxf(m3, a3);
        }
        WAVE_MAX4(m0, m1, m2, m3)
        float s0 = 0.f, s1 = 0.f, s2 = 0.f, s3 = 0.f;
        for (int b = 0; b < deg; b += 64) {
            float a0, a1, a2, a3;
            if (b + ln < deg) {
                logits(r0 + b + ln, a0, a1, a2, a3);
                s0 += __expf(a0 - m0); s1 += __expf(a1 - m1);
                s2 += __expf(a2 - m2); s3 += __expf(a3 - m3);
            }
        }
        WAVE_SUM4(s0, s1, s2, s3)
        sc0 = 0.25f / (s0 + 1e-9f); sc1 = 0.25f / (s1 + 1e-9f);
        sc2 = 0.25f / (s2 + 1e-9f); sc3 = 0.25f / (s3 + 1e-9f);
        for (int b = 0; b < deg; b += 64) {
            int sidx = 0;
            float e0 = 0.f, e1 = 0.f, e2 = 0.f, e3 = 0.f;
            if (b + ln < deg) {
                float a0, a1, a2, a3;
                sidx = logits(r0 + b + ln, a0, a1, a2, a3);
                e0 = __expf(a0 - m0); e1 = __expf(a1 - m1);
                e2 = __expf(a2 - m2); e3 = __expf(a3 - m3);
            }
            int cnt = deg - b; if (cnt > 64) cnt = 64;
            gather256((cnt + 1) >> 1, cnt, half, h, sidx, e0, e1, e2, e3, basep, acc);
        }
    }

    // per-head scale + head-mean (xor16, xor32); halves combined via LDS
    float scl = hsel(h, sc0, sc1, sc2, sc3);
    float t[16];
    #pragma unroll
    for (int i = 0; i < 16; ++i) {
        float v = acc[i] * scl;
        v += __shfl_xor(v, 16);
        v += __shfl_xor(v, 32);
        t[i] = v;
    }
    if (half == 1 && ln < 16) {
        #pragma unroll
        for (int i = 0; i < 16; ++i) red[slot][ln * 16 + i] = t[i];
    }
    __syncthreads();
    if (half == 0 && ln < 16) {
        int d0 = ln * 16;
        const float* yr = yres + (size_t)n * 256 + d0;
        float* yo = yout + (size_t)n * 256 + d0;
        #pragma unroll
        for (int q = 0; q < 4; ++q) {
            float4 ya = *(const float4*)(yr + 4 * q);
            float4 ov;
            ov.x = fmaxf(ya.x + t[4 * q + 0] + red[slot][d0 + 4 * q + 0], 0.f);
            ov.y = fmaxf(ya.y + t[4 * q + 1] + red[slot][d0 + 4 * q + 1], 0.f);
            ov.z = fmaxf(ya.z + t[4 * q + 2] + red[slot][d0 + 4 * q + 2], 0.f);
            ov.w = fmaxf(ya.w + t[4 * q + 3] + red[slot][d0 + 4 * q + 3], 0.f);
            *(float4*)(yo + 4 * q) = ov;
        }
    }
}

// ---------------------------------------------------------------- host side
extern "C" void kernel_launch(void* const* d_in, const int* in_sizes, int n_in,
                              void* d_out, int out_size, void* d_ws, size_t ws_size,
                              hipStream_t stream) {
    const float* node_feats = (const float*)d_in[0];
    const float* edge_feats = (const float*)d_in[1];
    const int*   src        = (const int*)d_in[2];
    const int*   dst        = (const int*)d_in[3];
    const float* W1   = (const float*)d_in[4];
    const float* We1  = (const float*)d_in[5];
    const float* al1  = (const float*)d_in[6];
    const float* ar1  = (const float*)d_in[7];
    const float* ae1  = (const float*)d_in[8];
    const float* res1 = (const float*)d_in[9];
    const float* W2   = (const float*)d_in[10];
    const float* al2  = (const float*)d_in[11];
    const float* ar2  = (const float*)d_in[12];
    const float* res2 = (const float*)d_in[13];
    const float* W3   = (const float*)d_in[14];
    const float* al3  = (const float*)d_in[15];
    const float* ar3  = (const float*)d_in[16];
    const float* res3 = (const float*)d_in[17];
    const float* W4   = (const float*)d_in[18];
    const float* al4  = (const float*)d_in[19];
    const float* ar4  = (const float*)d_in[20];
    const float* res4 = (const float*)d_in[21];

    char* ws = (char*)d_ws;
    auto alloc = [&](size_t bytes) -> char* {
        char* p = ws;
        ws += (bytes + 255) & ~(size_t)255;
        return p;
    };
    int*   counts  = (int*)alloc((size_t)NN * 4);
    int*   offsets = (int*)alloc((size_t)(NN + 1) * 4);
    int*   cursor  = (int*)alloc((size_t)(NN + 1) * 4);
    int*   ssrc    = (int*)alloc((size_t)EE * 4);
    unsigned char* featq = (unsigned char*)alloc((size_t)NN * 1024);
    float* xA      = (float*)alloc((size_t)NN * 128 * 4);
    short* xb      = (short*)alloc((size_t)NN * 128 * 2);
    float* elr     = (float*)alloc((size_t)NN * 8 * 4);
    float* extra   = (float*)alloc((size_t)EE * 4 * 4);
    float* vbuf    = (float*)alloc(1024);
    short* Wc1     = (short*)alloc((size_t)704 * 128 * 2);
    short* Wc2     = (short*)alloc((size_t)704 * 128 * 2);
    short* Wc3     = (short*)alloc((size_t)704 * 128 * 2);
    short* Wc4     = (short*)alloc((size_t)1344 * 128 * 2);

    PrepParams P;
    P.tsrc[0] = W1;   P.tdst[0] = Wc1;              P.tN[0] = 512;  P.tshift[0] = 9;
    P.tsrc[1] = W2;   P.tdst[1] = Wc2;              P.tN[1] = 512;  P.tshift[1] = 9;
    P.tsrc[2] = W3;   P.tdst[2] = Wc3;              P.tN[2] = 512;  P.tshift[2] = 9;
    P.tsrc[3] = W4;   P.tdst[3] = Wc4;              P.tN[3] = 1024; P.tshift[3] = 10;
    P.tsrc[4] = res1; P.tdst[4] = Wc1 + 512 * 128;  P.tN[4] = 128;  P.tshift[4] = 7;
    P.tsrc[5] = res2; P.tdst[5] = Wc2 + 512 * 128;  P.tN[5] = 128;  P.tshift[5] = 7;
    P.tsrc[6] = res3; P.tdst[6] = Wc3 + 512 * 128;  P.tN[6] = 128;  P.tshift[6] = 7;
    P.tsrc[7] = res4; P.tdst[7] = Wc4 + 1024 * 128; P.tN[7] = 256;  P.tshift[7] = 8;
    P.tcum4[0] = 0;
    for (int i = 0; i < 8; ++i) P.tcum4[i + 1] = P.tcum4[i] + P.tN[i] * 128 / 4;
    P.W[0] = W1; P.W[1] = W2; P.W[2] = W3; P.W[3] = W4;
    P.al[0] = al1; P.al[1] = al2; P.al[2] = al3; P.al[3] = al4;
    P.ar[0] = ar1; P.ar[1] = ar2; P.ar[2] = ar3; P.ar[3] = ar4;
    P.Wc[0] = Wc1; P.Wc[1] = Wc2; P.Wc[2] = Wc3; P.Wc[3] = Wc4;
    P.Dl[0] = 128; P.Dl[1] = 128; P.Dl[2] = 128; P.Dl[3] = 256;
    P.base[0] = 640; P.base[1] = 640; P.base[2] = 640; P.base[3] = 1280;
    P.We1 = We1; P.ae1 = ae1; P.vbuf = vbuf;
    P.node_feats = node_feats; P.xb = xb;
    P.counts = counts;
    P.bWA = (P.tcum4[8] + 255) / 256;
    P.bV  = P.bWA + 512;
    P.bC  = P.bV + 16;
    P.bZ  = P.bC + (NN * 32 + 255) / 256;
    int nblk = P.bZ + (NN / 4 + 255) / 256;
    prep_kernel<<<nblk, 256, 0, stream>>>(P);

    hist_kernel<<<(EE + 255) / 256, 256, 0, stream>>>(dst, counts, EE);
    scan_kernel<<<1, 256, 0, stream>>>(counts, offsets, cursor, NN);
    fill_extra<<<(EE + 255) / 256, 256, 0, stream>>>(src, dst, cursor, edge_feats,
                                                     vbuf, ssrc, extra, EE);

    float* out = (float*)d_out;
    dim3 g128(11, (NN + 63) / 64);
    dim3 g256(21, (NN + 63) / 64);
    int gs128 = NN / 4;   // 4 nodes/block, 1 wave each
    int gs256 = NN / 2;   // 2 nodes/block, 2 waves each

    // ---- layer 1
    gemm_fused<128><<<g128, 256, 0, stream>>>(xb, Wc1, featq, xA, elr, NN);
    gat128<true><<<gs128, 256, 0, stream>>>(featq, elr, extra, ssrc, offsets, xA, xb);
    // ---- layer 2
    gemm_fused<128><<<g128, 256, 0, stream>>>(xb, Wc2, featq, xA, elr, NN);
    gat128<false><<<gs128, 256, 0, stream>>>(featq, elr, nullptr, ssrc, offsets, xA, xb);
    // ---- layer 3
    gemm_fused<128><<<g128, 256, 0, stream>>>(xb, Wc3, featq, xA, elr, NN);
    gat128<false><<<gs128, 256, 0, stream>>>(featq, elr, nullptr, ssrc, offsets, xA, xb);
    // ---- layer 4
    gemm_fused<256><<<g256, 256, 0, stream>>>(xb, Wc4, featq, out, elr, NN);
    gat256<<<gs256, 256, 0, stream>>>(featq, elr, ssrc, offsets, out, out);
}

// Round 12
// 366.029 us; speedup vs baseline: 1.0960x; 1.0011x over previous
//
#include <hip/hip_runtime.h>

#define NN 10000
#define EE 160000

typedef __attribute__((ext_vector_type(8))) short bf16x8;
typedef __attribute__((ext_vector_type(4))) float f32x4;
typedef __attribute__((ext_vector_type(2))) float f32x2;

__device__ __forceinline__ float b2f(unsigned short s) {
    union { unsigned u; float f; } v; v.u = ((unsigned)s) << 16; return v.f;
}
__device__ __forceinline__ short f2b(float f) {
    union { float f; unsigned u; } v; v.f = f;
    unsigned r = v.u + 0x7FFF + ((v.u >> 16) & 1);  // RNE
    return (short)(r >> 16);
}
// fp8 e4m3 (OCP) encode via HW converter; returns low byte
__device__ __forceinline__ unsigned char f2q(float f) {
    return (unsigned char)(__builtin_amdgcn_cvt_pk_fp8_f32(f, f, 0, false) & 0xFF);
}

// ---------------------------------------------------------------- CSR build
__global__ __launch_bounds__(256) void hist_kernel(const int* __restrict__ dst,
                                                   int* __restrict__ counts, int E) {
    int e = blockIdx.x * 256 + threadIdx.x;
    if (e < E) atomicAdd(&counts[dst[e]], 1);
}

// LDS-staged single-block scan
__global__ __launch_bounds__(256) void scan_kernel(const int* __restrict__ counts,
                                                   int* __restrict__ off,
                                                   int* __restrict__ cur, int n) {
    __shared__ int buf[NN];
    __shared__ int part[256];
    int tid = threadIdx.x;
    for (int j = tid; j < n; j += 256) buf[j] = counts[j];
    __syncthreads();
    int chunk = (n + 255) / 256;
    int lo = tid * chunk; if (lo > n) lo = n;
    int hi = lo + chunk;  if (hi > n) hi = n;
    int s = 0;
    for (int i = lo; i < hi; ++i) s += buf[i];
    part[tid] = s;
    __syncthreads();
    for (int o = 1; o < 256; o <<= 1) {
        int v = (tid >= o) ? part[tid - o] : 0;
        __syncthreads();
        part[tid] += v;
        __syncthreads();
    }
    int run = (tid == 0) ? 0 : part[tid - 1];
    for (int i = lo; i < hi; ++i) { int c = buf[i]; buf[i] = run; run += c; }
    __syncthreads();
    for (int j = tid; j < n; j += 256) { int v = buf[j]; off[j] = v; cur[j] = v; }
    if (tid == 255) off[n] = part[255];
}

// fill + layer-1 edge-extra fused
__global__ __launch_bounds__(256) void fill_extra(const int* __restrict__ src,
                                                  const int* __restrict__ dst,
                                                  int* __restrict__ cur,
                                                  const float* __restrict__ ef,
                                                  const float* __restrict__ vbuf,
                                                  int* __restrict__ ssrc,
                                                  float* __restrict__ extra, int E) {
    __shared__ float vs[256];
    vs[threadIdx.x] = vbuf[threadIdx.x];
    __syncthreads();
    int e = blockIdx.x * 256 + threadIdx.x;
    if (e >= E) return;
    int p = atomicAdd(&cur[dst[e]], 1);
    ssrc[p] = src[e];
    float a0 = 0.f, a1 = 0.f, a2 = 0.f, a3 = 0.f;
    const float4* e4 = (const float4*)(ef + (size_t)e * 64);
    #pragma unroll
    for (int c = 0; c < 16; ++c) {
        float4 x = e4[c];
        int b = c * 16;
        a0 += x.x * vs[b + 0] + x.y * vs[b + 4] + x.z * vs[b + 8] + x.w * vs[b + 12];
        a1 += x.x * vs[b + 1] + x.y * vs[b + 5] + x.z * vs[b + 9] + x.w * vs[b + 13];
        a2 += x.x * vs[b + 2] + x.y * vs[b + 6] + x.z * vs[b + 10] + x.w * vs[b + 14];
        a3 += x.x * vs[b + 3] + x.y * vs[b + 7] + x.z * vs[b + 11] + x.w * vs[b + 15];
    }
    float4 o; o.x = a0; o.y = a1; o.z = a2; o.w = a3;
    *(float4*)(extra + (size_t)p * 4) = o;
}

// --------------------------- one prep kernel, all branches wave-parallel
struct PrepParams {
    const float* tsrc[8];
    short* tdst[8];
    int tN[8];
    int tshift[8];
    int tcum4[9];
    const float* W[4]; const float* al[4]; const float* ar[4];
    short* Wc[4]; int Dl[4]; int base[4];
    const float* We1; const float* ae1; float* vbuf;
    const float* node_feats; short* xb;
    int* counts;
    int bWA, bV, bC, bZ;
};
__global__ __launch_bounds__(256) void prep_kernel(PrepParams P) {
    int blk = blockIdx.x, tid = threadIdx.x;
    if (blk < P.bWA) {
        int t = blk * 256 + tid;
        if (t >= P.tcum4[8]) return;
        int i = 0;
        #pragma unroll
        for (int j = 1; j < 8; ++j) i += (t >= P.tcum4[j]);
        int local = t - P.tcum4[i];
        int N = P.tN[i], sh = P.tshift[i];
        int k = local >> (sh - 2);
        int nq = local & ((N >> 2) - 1);
        float4 v = *(const float4*)(P.tsrc[i] + (size_t)k * N + nq * 4);
        short* d = P.tdst[i] + (size_t)nq * 4 * 128 + k;
        d[0] = f2b(v.x); d[128] = f2b(v.y); d[256] = f2b(v.z); d[384] = f2b(v.w);
    } else if (blk < P.bV) {
        int bl = blk - P.bWA;
        int l = bl >> 7, within = bl & 127;
        int wv = tid >> 6, ln = tid & 63;
        int wid = within * 4 + wv;
        int k = wid >> 2, h = wid & 3;
        int D = P.Dl[l];
        const float* w = P.W[l] + ((size_t)k * 4 + h) * D;
        const float* a = P.al[l] + (size_t)h * D;
        const float* r = P.ar[l] + (size_t)h * D;
        float sa, sr;
        if (D == 128) {
            float2 w2 = ((const float2*)w)[ln];
            float2 a2 = ((const float2*)a)[ln];
            float2 r2 = ((const float2*)r)[ln];
            sa = w2.x * a2.x + w2.y * a2.y;
            sr = w2.x * r2.x + w2.y * r2.y;
        } else {
            float4 w4 = ((const float4*)w)[ln];
            float4 a4 = ((const float4*)a)[ln];
            float4 r4 = ((const float4*)r)[ln];
            sa = w4.x * a4.x + w4.y * a4.y + w4.z * a4.z + w4.w * a4.w;
            sr = w4.x * r4.x + w4.y * r4.y + w4.z * r4.z + w4.w * r4.w;
        }
        #pragma unroll
        for (int o = 32; o; o >>= 1) { sa += __shfl_xor(sa, o); sr += __shfl_xor(sr, o); }
        if (ln == 0) {
            P.Wc[l][(size_t)(P.base[l] + h) * 128 + k]     = f2b(sa);
            P.Wc[l][(size_t)(P.base[l] + 4 + h) * 128 + k] = f2b(sr);
        }
    } else if (blk < P.bC) {
        int bl = blk - P.bV;
        int wv = tid >> 6, ln = tid & 63;
        int i = bl * 4 + wv;
        #pragma unroll
        for (int h = 0; h < 4; ++h) {
            const float* w = P.We1 + ((size_t)i * 4 + h) * 128;
            const float* a = P.ae1 + (size_t)h * 128;
            float2 w2 = ((const float2*)w)[ln];
            float2 a2 = ((const float2*)a)[ln];
            float s = w2.x * a2.x + w2.y * a2.y;
            #pragma unroll
            for (int o = 32; o; o >>= 1) s += __shfl_xor(s, o);
            if (ln == 0) P.vbuf[i * 4 + h] = s;
        }
    } else if (blk < P.bZ) {
        int t = (blk - P.bC) * 256 + tid;
        if (t < NN * 32) {
            float4 v = ((const float4*)P.node_feats)[t];
            uint2 pk;
            pk.x = (unsigned short)f2b(v.x) | ((unsigned)(unsigned short)f2b(v.y) << 16);
            pk.y = (unsigned short)f2b(v.z) | ((unsigned)(unsigned short)f2b(v.w) << 16);
            ((uint2*)P.xb)[t] = pk;
        }
    } else {
        int t = (blk - P.bZ) * 256 + tid;
        if (t < NN / 4) ((int4*)P.counts)[t] = make_int4(0, 0, 0, 0);
    }
}

// ---------------- fused GEMM: feat (fp8 e4m3) + res (f32) + el/er (f32)
template <int D>
__global__ __launch_bounds__(256) void gemm_fused(const short* __restrict__ A,
                                                  const short* __restrict__ Bt,
                                                  unsigned char* __restrict__ featq,
                                                  float* __restrict__ y,
                                                  float* __restrict__ elr,
                                                  int M) {
    constexpr int HD = 4 * D;
    int wave = threadIdx.x >> 6, lane = threadIdx.x & 63;
    int m0 = blockIdx.y * 64;
    int n0 = blockIdx.x * 64 + wave * 16;
    int r = lane & 15, quad = lane >> 4;
    f32x4 acc[4] = {};
    const short* bp = Bt + (size_t)(n0 + r) * 128 + quad * 8;
    #pragma unroll
    for (int k0 = 0; k0 < 128; k0 += 32) {
        bf16x8 bfrag = *(const bf16x8*)(bp + k0);
        #pragma unroll
        for (int mt = 0; mt < 4; ++mt) {
            int gm = m0 + mt * 16 + r;
            bf16x8 afrag = {};
            if (gm < M) afrag = *(const bf16x8*)(A + (size_t)gm * 128 + k0 + quad * 8);
            acc[mt] = __builtin_amdgcn_mfma_f32_16x16x32_bf16(afrag, bfrag, acc[mt], 0, 0, 0);
        }
    }
    int col = n0 + r;
    #pragma unroll
    for (int mt = 0; mt < 4; ++mt) {
        #pragma unroll
        for (int rr = 0; rr < 4; ++rr) {
            int gm = m0 + mt * 16 + quad * 4 + rr;
            if (gm >= M) continue;
            float v = acc[mt][rr];
            if (col < HD)              featq[(size_t)gm * HD + col] = f2q(v);
            else if (col < HD + D)     y[(size_t)gm * D + (col - HD)] = v;
            else if (col < HD + D + 8) elr[(size_t)gm * 8 + (col - HD - D)] = v;
        }
    }
}

// ------------------------------------------------- gather helpers (fp8, 16/lane)
__device__ __forceinline__ void accum16q(float* a, uint4 v, float w) {
    f32x2 p;
    p = __builtin_amdgcn_cvt_pk_f32_fp8(v.x, false); a[0] += w * p.x; a[1] += w * p.y;
    p = __builtin_amdgcn_cvt_pk_f32_fp8(v.x, true);  a[2] += w * p.x; a[3] += w * p.y;
    p = __builtin_amdgcn_cvt_pk_f32_fp8(v.y, false); a[4] += w * p.x; a[5] += w * p.y;
    p = __builtin_amdgcn_cvt_pk_f32_fp8(v.y, true);  a[6] += w * p.x; a[7] += w * p.y;
    p = __builtin_amdgcn_cvt_pk_f32_fp8(v.z, false); a[8] += w * p.x; a[9] += w * p.y;
    p = __builtin_amdgcn_cvt_pk_f32_fp8(v.z, true);  a[10] += w * p.x; a[11] += w * p.y;
    p = __builtin_amdgcn_cvt_pk_f32_fp8(v.w, false); a[12] += w * p.x; a[13] += w * p.y;
    p = __builtin_amdgcn_cvt_pk_f32_fp8(v.w, true);  a[14] += w * p.x; a[15] += w * p.y;
}

// All __shfl executed by the FULL wave with uniform trip counts; invalid
// edges are clamped+zero-masked (never EXEC-masked) — R7 lesson.
__device__ __forceinline__ float hsel(int h, float s0, float s1, float s2, float s3) {
    return h == 0 ? s0 : h == 1 ? s1 : h == 2 ? s2 : s3;
}

// gat128 gather: lane group g=ln>>5 covers full 512B row; edge 2*it+g
__device__ __forceinline__ void gather128(int T, int deg, int g, int h, int sidx,
                                          float e0, float e1, float e2, float e3,
                                          const unsigned char* __restrict__ basep,
                                          float acc[16]) {
    int it = 0;
    for (; it + 4 <= T; it += 4) {
        int j0 = 2 * it + g, j1 = j0 + 2, j2 = j0 + 4, j3 = j0 + 6;
        int c0 = j0 < deg ? j0 : deg - 1;
        int c1 = j1 < deg ? j1 : deg - 1;
        int c2 = j2 < deg ? j2 : deg - 1;
        int c3 = j3 < deg ? j3 : deg - 1;
        float m0 = j0 < deg ? 1.f : 0.f, m1 = j1 < deg ? 1.f : 0.f;
        float m2 = j2 < deg ? 1.f : 0.f, m3 = j3 < deg ? 1.f : 0.f;
        int s0 = __shfl(sidx, c0), s1 = __shfl(sidx, c1);
        int s2 = __shfl(sidx, c2), s3 = __shfl(sidx, c3);
        uint4 v0 = *(const uint4*)(basep + (size_t)s0 * 512);
        uint4 v1 = *(const uint4*)(basep + (size_t)s1 * 512);
        uint4 v2 = *(const uint4*)(basep + (size_t)s2 * 512);
        uint4 v3 = *(const uint4*)(basep + (size_t)s3 * 512);
        float w0 = hsel(h, __shfl(e0, c0), __shfl(e1, c0), __shfl(e2, c0), __shfl(e3, c0)) * m0;
        float w1 = hsel(h, __shfl(e0, c1), __shfl(e1, c1), __shfl(e2, c1), __shfl(e3, c1)) * m1;
        float w2 = hsel(h, __shfl(e0, c2), __shfl(e1, c2), __shfl(e2, c2), __shfl(e3, c2)) * m2;
        float w3 = hsel(h, __shfl(e0, c3), __shfl(e1, c3), __shfl(e2, c3), __shfl(e3, c3)) * m3;
        accum16q(acc, v0, w0); accum16q(acc, v1, w1);
        accum16q(acc, v2, w2); accum16q(acc, v3, w3);
    }
    for (; it < T; ++it) {
        int j0 = 2 * it + g;
        int c0 = j0 < deg ? j0 : deg - 1;
        float m0 = j0 < deg ? 1.f : 0.f;
        int s0 = __shfl(sidx, c0);
        uint4 v0 = *(const uint4*)(basep + (size_t)s0 * 512);
        float w0 = hsel(h, __shfl(e0, c0), __shfl(e1, c0), __shfl(e2, c0), __shfl(e3, c0)) * m0;
        accum16q(acc, v0, w0);
    }
}

// gat256 gather: whole wave covers full 1024B row; edge 2*it+half
__device__ __forceinline__ void gather256(int T, int deg, int half, int h, int sidx,
                                          float e0, float e1, float e2, float e3,
                                          const unsigned char* __restrict__ basep,
                                          float acc[16]) {
    int it = 0;
    for (; it + 4 <= T; it += 4) {
        int j0 = 2 * it + half, j1 = j0 + 2, j2 = j0 + 4, j3 = j0 + 6;
        int c0 = j0 < deg ? j0 : deg - 1;
        int c1 = j1 < deg ? j1 : deg - 1;
        int c2 = j2 < deg ? j2 : deg - 1;
        int c3 = j3 < deg ? j3 : deg - 1;
        float m0 = j0 < deg ? 1.f : 0.f, m1 = j1 < deg ? 1.f : 0.f;
        float m2 = j2 < deg ? 1.f : 0.f, m3 = j3 < deg ? 1.f : 0.f;
        int s0 = __shfl(sidx, c0), s1 = __shfl(sidx, c1);
        int s2 = __shfl(sidx, c2), s3 = __shfl(sidx, c3);
        uint4 v0 = *(const uint4*)(basep + (size_t)s0 * 1024);
        uint4 v1 = *(const uint4*)(basep + (size_t)s1 * 1024);
        uint4 v2 = *(const uint4*)(basep + (size_t)s2 * 1024);
        uint4 v3 = *(const uint4*)(basep + (size_t)s3 * 1024);
        float w0 = hsel(h, __shfl(e0, c0), __shfl(e1, c0), __shfl(e2, c0), __shfl(e3, c0)) * m0;
        float w1 = hsel(h, __shfl(e0, c1), __shfl(e1, c1), __shfl(e2, c1), __shfl(e3, c1)) * m1;
        float w2 = hsel(h, __shfl(e0, c2), __shfl(e1, c2), __shfl(e2, c2), __shfl(e3, c2)) * m2;
        float w3 = hsel(h, __shfl(e0, c3), __shfl(e1, c3), __shfl(e2, c3), __shfl(e3, c3)) * m3;
        accum16q(acc, v0, w0); accum16q(acc, v1, w1);
        accum16q(acc, v2, w2); accum16q(acc, v3, w3);
    }
    for (; it < T; ++it) {
        int j0 = 2 * it + half;
        int c0 = j0 < deg ? j0 : deg - 1;
        float m0 = j0 < deg ? 1.f : 0.f;
        int s0 = __shfl(sidx, c0);
        uint4 v0 = *(const uint4*)(basep + (size_t)s0 * 1024);
        float w0 = hsel(h, __shfl(e0, c0), __shfl(e1, c0), __shfl(e2, c0), __shfl(e3, c0)) * m0;
        accum16q(acc, v0, w0);
    }
}

#define WAVE_MAX4(m0,m1,m2,m3)                                              \
    _Pragma("unroll")                                                       \
    for (int o = 32; o; o >>= 1) {                                          \
        m0 = fmaxf(m0, __shfl_xor(m0, o)); m1 = fmaxf(m1, __shfl_xor(m1, o));\
        m2 = fmaxf(m2, __shfl_xor(m2, o)); m3 = fmaxf(m3, __shfl_xor(m3, o));\
    }
#define WAVE_SUM4(s0,s1,s2,s3)                                              \
    _Pragma("unroll")                                                       \
    for (int o = 32; o; o >>= 1) {                                          \
        s0 += __shfl_xor(s0, o); s1 += __shfl_xor(s1, o);                   \
        s2 += __shfl_xor(s2, o); s3 += __shfl_xor(s3, o);                   \
    }

// ---------------- D=128 layers: 1 wave per node, dual-edge lanes, no LDS
template <bool HAS_EXTRA>
__global__ __launch_bounds__(256) void gat128(const unsigned char* __restrict__ featq,
                                              const float* __restrict__ elr,
                                              const float* __restrict__ extra,
                                              const int* __restrict__ ssrc,
                                              const int* __restrict__ off,
                                              const float* __restrict__ yres,
                                              short* __restrict__ ybf) {
    int wv = threadIdx.x >> 6, ln = threadIdx.x & 63;
    int n = blockIdx.x * 4 + wv;
    int r0 = off[n], deg = off[n + 1] - r0;
    int g = ln >> 5, l5 = ln & 31;
    int h = l5 >> 3;
    float4 erv = *(const float4*)(elr + (size_t)n * 8 + 4);
    float acc[16];
    #pragma unroll
    for (int i = 0; i < 16; ++i) acc[i] = 0.f;
    float sc0, sc1, sc2, sc3;
    const unsigned char* basep = featq + l5 * 16;

    auto logits = [&](int idx, float& a0, float& a1, float& a2, float& a3) {
        int s = ssrc[idx];
        float4 elv = *(const float4*)(elr + (size_t)s * 8);
        a0 = elv.x + erv.x; a1 = elv.y + erv.y; a2 = elv.z + erv.z; a3 = elv.w + erv.w;
        if (HAS_EXTRA) {
            float4 exv = *(const float4*)(extra + (size_t)idx * 4);
            a0 += exv.x; a1 += exv.y; a2 += exv.z; a3 += exv.w;
        }
        a0 = a0 > 0.f ? a0 : 0.2f * a0;
        a1 = a1 > 0.f ? a1 : 0.2f * a1;
        a2 = a2 > 0.f ? a2 : 0.2f * a2;
        a3 = a3 > 0.f ? a3 : 0.2f * a3;
        return s;
    };

    if (deg <= 64) {
        int sidx = 0;
        float a0 = -1e30f, a1 = -1e30f, a2 = -1e30f, a3 = -1e30f;
        if (ln < deg) sidx = logits(r0 + ln, a0, a1, a2, a3);
        float m0 = a0, m1 = a1, m2 = a2, m3 = a3;
        WAVE_MAX4(m0, m1, m2, m3)
        float e0 = 0.f, e1 = 0.f, e2 = 0.f, e3 = 0.f;
        if (ln < deg) {
            e0 = __expf(a0 - m0); e1 = __expf(a1 - m1);
            e2 = __expf(a2 - m2); e3 = __expf(a3 - m3);
        }
        float s0 = e0, s1 = e1, s2 = e2, s3 = e3;
        WAVE_SUM4(s0, s1, s2, s3)
        sc0 = 0.25f / (s0 + 1e-9f); sc1 = 0.25f / (s1 + 1e-9f);
        sc2 = 0.25f / (s2 + 1e-9f); sc3 = 0.25f / (s3 + 1e-9f);
        gather128((deg + 1) >> 1, deg, g, h, sidx, e0, e1, e2, e3, basep, acc);
    } else {
        float m0 = -1e30f, m1 = -1e30f, m2 = -1e30f, m3 = -1e30f;
        for (int b = 0; b < deg; b += 64) {
            float a0 = -1e30f, a1 = -1e30f, a2 = -1e30f, a3 = -1e30f;
            if (b + ln < deg) logits(r0 + b + ln, a0, a1, a2, a3);
            m0 = fmaxf(m0, a0); m1 = fmaxf(m1, a1); m2 = fmaxf(m2, a2); m3 = fmaxf(m3, a3);
        }
        WAVE_MAX4(m0, m1, m2, m3)
        float s0 = 0.f, s1 = 0.f, s2 = 0.f, s3 = 0.f;
        for (int b = 0; b < deg; b += 64) {
            float a0, a1, a2, a3;
            if (b + ln < deg) {
                logits(r0 + b + ln, a0, a1, a2, a3);
                s0 += __expf(a0 - m0); s1 += __expf(a1 - m1);
                s2 += __expf(a2 - m2); s3 += __expf(a3 - m3);
            }
        }
        WAVE_SUM4(s0, s1, s2, s3)
        sc0 = 0.25f / (s0 + 1e-9f); sc1 = 0.25f / (s1 + 1e-9f);
        sc2 = 0.25f / (s2 + 1e-9f); sc3 = 0.25f / (s3 + 1e-9f);
        for (int b = 0; b < deg; b += 64) {
            int sidx = 0;
            float e0 = 0.f, e1 = 0.f, e2 = 0.f, e3 = 0.f;
            if (b + ln < deg) {
                float a0, a1, a2, a3;
                sidx = logits(r0 + b + ln, a0, a1, a2, a3);
                e0 = __expf(a0 - m0); e1 = __expf(a1 - m1);
                e2 = __expf(a2 - m2); e3 = __expf(a3 - m3);
            }
            int cnt = deg - b; if (cnt > 64) cnt = 64;
            gather128((cnt + 1) >> 1, cnt, g, h, sidx, e0, e1, e2, e3, basep, acc);
        }
    }

    // per-head scale, then group-sum (xor32) + head-mean (xor8, xor16)
    float scl = hsel(h, sc0, sc1, sc2, sc3);
    float t[16];
    #pragma unroll
    for (int i = 0; i < 16; ++i) {
        float v = acc[i] * scl;
        v += __shfl_xor(v, 32);
        v += __shfl_xor(v, 8);
        v += __shfl_xor(v, 16);
        t[i] = v;
    }
    if (ln < 8) {
        int d0 = ln * 16;
        const float* yr = yres + (size_t)n * 128 + d0;
        unsigned pk[8];
        #pragma unroll
        for (int q = 0; q < 8; ++q) {
            float ya = yr[2 * q], yb = yr[2 * q + 1];
            float o0 = fmaxf(ya + t[2 * q], 0.f);
            float o1 = fmaxf(yb + t[2 * q + 1], 0.f);
            pk[q] = (unsigned short)f2b(o0) | ((unsigned)(unsigned short)f2b(o1) << 16);
        }
        uint4 pa, pb;
        pa.x = pk[0]; pa.y = pk[1]; pa.z = pk[2]; pa.w = pk[3];
        pb.x = pk[4]; pb.y = pk[5]; pb.z = pk[6]; pb.w = pk[7];
        *(uint4*)(ybf + (size_t)n * 128 + d0) = pa;
        *(uint4*)(ybf + (size_t)n * 128 + d0 + 8) = pb;
    }
}

// ---------------- D=256 layer 4: 2 waves/node edge-split, full-row lanes
__global__ __launch_bounds__(256) void gat256(const unsigned char* __restrict__ featq,
                                              const float* __restrict__ elr,
                                              const int* __restrict__ ssrc,
                                              const int* __restrict__ off,
                                              const float* __restrict__ yres,
                                              float* __restrict__ yout) {
    __shared__ float red[2][256];
    int wv = threadIdx.x >> 6, ln = threadIdx.x & 63;
    int slot = wv >> 1, half = wv & 1;
    int n = blockIdx.x * 2 + slot;
    int r0 = off[n], deg = off[n + 1] - r0;
    int h = ln >> 4;
    float4 erv = *(const float4*)(elr + (size_t)n * 8 + 4);
    float acc[16];
    #pragma unroll
    for (int i = 0; i < 16; ++i) acc[i] = 0.f;
    float sc0, sc1, sc2, sc3;
    const unsigned char* basep = featq + ln * 16;

    auto logits = [&](int idx, float& a0, float& a1, float& a2, float& a3) {
        int s = ssrc[idx];
        float4 elv = *(const float4*)(elr + (size_t)s * 8);
        a0 = elv.x + erv.x; a1 = elv.y + erv.y; a2 = elv.z + erv.z; a3 = elv.w + erv.w;
        a0 = a0 > 0.f ? a0 : 0.2f * a0;
        a1 = a1 > 0.f ? a1 : 0.2f * a1;
        a2 = a2 > 0.f ? a2 : 0.2f * a2;
        a3 = a3 > 0.f ? a3 : 0.2f * a3;
        return s;
    };

    if (deg <= 64) {
        int sidx = 0;
        float a0 = -1e30f, a1 = -1e30f, a2 = -1e30f, a3 = -1e30f;
        if (ln < deg) sidx = logits(r0 + ln, a0, a1, a2, a3);
        float m0 = a0, m1 = a1, m2 = a2, m3 = a3;
        WAVE_MAX4(m0, m1, m2, m3)
        float e0 = 0.f, e1 = 0.f, e2 = 0.f, e3 = 0.f;
        if (ln < deg) {
            e0 = __expf(a0 - m0); e1 = __expf(a1 - m1);
            e2 = __expf(a2 - m2); e3 = __expf(a3 - m3);
        }
        float s0 = e0, s1 = e1, s2 = e2, s3 = e3;
        WAVE_SUM4(s0, s1, s2, s3)
        sc0 = 0.25f / (s0 + 1e-9f); sc1 = 0.25f / (s1 + 1e-9f);
        sc2 = 0.25f / (s2 + 1e-9f); sc3 = 0.25f / (s3 + 1e-9f);
        gather256((deg + 1) >> 1, deg, half, h, sidx, e0, e1, e2, e3, basep, acc);
    } else {
        float m0 = -1e30f, m1 = -1e30f, m2 = -1e30f, m3 = -1e30f;
        for (int b = 0; b < deg; b += 64) {
            float a0 = -1e30f, a1 = -1e30f, a2 = -1e30f, a3 = -1e30f;
            if (b + ln < deg) logits(r0 + b + ln, a0, a1, a2, a3);
            m0 = fmaxf(m0, a0); m1 = fmaxf(m1, a1); m2 = fmaxf(m2, a2); m3 = fmaxf(m3, a3);
        }
        WAVE_MAX4(m0, m1, m2, m3)
        float s0 = 0.f, s1 = 0.f, s2 = 0.f, s3 = 0.f;
        for (int b = 0; b < deg; b += 64) {
            float a0, a1, a2, a3;
            if (b + ln < deg) {
                logits(r0 + b + ln, a0, a1, a2, a3);
                s0 += __expf(a0 - m0); s1 += __expf(a1 - m1);
                s2 += __expf(a2 - m2); s3 += __expf(a3 - m3);
            }
        }
        WAVE_SUM4(s0, s1, s2, s3)
        sc0 = 0.25f / (s0 + 1e-9f); sc1 = 0.25f / (s1 + 1e-9f);
        sc2 = 0.25f / (s2 + 1e-9f); sc3 = 0.25f / (s3 + 1e-9f);
        for (int b = 0; b < deg; b += 64) {
            int sidx = 0;
            float e0 = 0.f, e1 = 0.f, e2 = 0.f, e3 = 0.f;
            if (b + ln < deg) {
                float a0, a1, a2, a3;
                sidx = logits(r0 + b + ln, a0, a1, a2, a3);
                e0 = __expf(a0 - m0); e1 = __expf(a1 - m1);
                e2 = __expf(a2 - m2); e3 = __expf(a3 - m3);
            }
            int cnt = deg - b; if (cnt > 64) cnt = 64;
            gather256((cnt + 1) >> 1, cnt, half, h, sidx, e0, e1, e2, e3, basep, acc);
        }
    }

    // per-head scale + head-mean (xor16, xor32); halves combined via LDS
    float scl = hsel(h, sc0, sc1, sc2, sc3);
    float t[16];
    #pragma unroll
    for (int i = 0; i < 16; ++i) {
        float v = acc[i] * scl;
        v += __shfl_xor(v, 16);
        v += __shfl_xor(v, 32);
        t[i] = v;
    }
    if (half == 1 && ln < 16) {
        #pragma unroll
        for (int i = 0; i < 16; ++i) red[slot][ln * 16 + i] = t[i];
    }
    __syncthreads();
    if (half == 0 && ln < 16) {
        int d0 = ln * 16;
        const float* yr = yres + (size_t)n * 256 + d0;
        float* yo = yout + (size_t)n * 256 + d0;
        #pragma unroll
        for (int q = 0; q < 4; ++q) {
            float4 ya = *(const float4*)(yr + 4 * q);
            float4 ov;
            ov.x = fmaxf(ya.x + t[4 * q + 0] + red[slot][d0 + 4 * q + 0], 0.f);
            ov.y = fmaxf(ya.y + t[4 * q + 1] + red[slot][d0 + 4 * q + 1], 0.f);
            ov.z = fmaxf(ya.z + t[4 * q + 2] + red[slot][d0 + 4 * q + 2], 0.f);
            ov.w = fmaxf(ya.w + t[4 * q + 3] + red[slot][d0 + 4 * q + 3], 0.f);
            *(float4*)(yo + 4 * q) = ov;
        }
    }
}

// ---------------------------------------------------------------- host side
extern "C" void kernel_launch(void* const* d_in, const int* in_sizes, int n_in,
                              void* d_out, int out_size, void* d_ws, size_t ws_size,
                              hipStream_t stream) {
    const float* node_feats = (const float*)d_in[0];
    const float* edge_feats = (const float*)d_in[1];
    const int*   src        = (const int*)d_in[2];
    const int*   dst        = (const int*)d_in[3];
    const float* W1   = (const float*)d_in[4];
    const float* We1  = (const float*)d_in[5];
    const float* al1  = (const float*)d_in[6];
    const float* ar1  = (const float*)d_in[7];
    const float* ae1  = (const float*)d_in[8];
    const float* res1 = (const float*)d_in[9];
    const float* W2   = (const float*)d_in[10];
    const float* al2  = (const float*)d_in[11];
    const float* ar2  = (const float*)d_in[12];
    const float* res2 = (const float*)d_in[13];
    const float* W3   = (const float*)d_in[14];
    const float* al3  = (const float*)d_in[15];
    const float* ar3  = (const float*)d_in[16];
    const float* res3 = (const float*)d_in[17];
    const float* W4   = (const float*)d_in[18];
    const float* al4  = (const float*)d_in[19];
    const float* ar4  = (const float*)d_in[20];
    const float* res4 = (const float*)d_in[21];

    char* ws = (char*)d_ws;
    auto alloc = [&](size_t bytes) -> char* {
        char* p = ws;
        ws += (bytes + 255) & ~(size_t)255;
        return p;
    };
    int*   counts  = (int*)alloc((size_t)NN * 4);
    int*   offsets = (int*)alloc((size_t)(NN + 1) * 4);
    int*   cursor  = (int*)alloc((size_t)(NN + 1) * 4);
    int*   ssrc    = (int*)alloc((size_t)EE * 4);
    unsigned char* featq = (unsigned char*)alloc((size_t)NN * 1024);
    float* xA      = (float*)alloc((size_t)NN * 128 * 4);
    short* xb      = (short*)alloc((size_t)NN * 128 * 2);
    float* elr     = (float*)alloc((size_t)NN * 8 * 4);
    float* extra   = (float*)alloc((size_t)EE * 4 * 4);
    float* vbuf    = (float*)alloc(1024);
    short* Wc1     = (short*)alloc((size_t)704 * 128 * 2);
    short* Wc2     = (short*)alloc((size_t)704 * 128 * 2);
    short* Wc3     = (short*)alloc((size_t)704 * 128 * 2);
    short* Wc4     = (short*)alloc((size_t)1344 * 128 * 2);

    PrepParams P;
    P.tsrc[0] = W1;   P.tdst[0] = Wc1;              P.tN[0] = 512;  P.tshift[0] = 9;
    P.tsrc[1] = W2;   P.tdst[1] = Wc2;              P.tN[1] = 512;  P.tshift[1] = 9;
    P.tsrc[2] = W3;   P.tdst[2] = Wc3;              P.tN[2] = 512;  P.tshift[2] = 9;
    P.tsrc[3] = W4;   P.tdst[3] = Wc4;              P.tN[3] = 1024; P.tshift[3] = 10;
    P.tsrc[4] = res1; P.tdst[4] = Wc1 + 512 * 128;  P.tN[4] = 128;  P.tshift[4] = 7;
    P.tsrc[5] = res2; P.tdst[5] = Wc2 + 512 * 128;  P.tN[5] = 128;  P.tshift[5] = 7;
    P.tsrc[6] = res3; P.tdst[6] = Wc3 + 512 * 128;  P.tN[6] = 128;  P.tshift[6] = 7;
    P.tsrc[7] = res4; P.tdst[7] = Wc4 + 1024 * 128; P.tN[7] = 256;  P.tshift[7] = 8;
    P.tcum4[0] = 0;
    for (int i = 0; i < 8; ++i) P.tcum4[i + 1] = P.tcum4[i] + P.tN[i] * 128 / 4;
    P.W[0] = W1; P.W[1] = W2; P.W[2] = W3; P.W[3] = W4;
    P.al[0] = al1; P.al[1] = al2; P.al[2] = al3; P.al[3] = al4;
    P.ar[0] = ar1; P.ar[1] = ar2; P.ar[2] = ar3; P.ar[3] = ar4;
    P.Wc[0] = Wc1; P.Wc[1] = Wc2; P.Wc[2] = Wc3; P.Wc[3] = Wc4;
    P.Dl[0] = 128; P.Dl[1] = 128; P.Dl[2] = 128; P.Dl[3] = 256;
    P.base[0] = 640; P.base[1] = 640; P.base[2] = 640; P.base[3] = 1280;
    P.We1 = We1; P.ae1 = ae1; P.vbuf = vbuf;
    P.node_feats = node_feats; P.xb = xb;
    P.counts = counts;
    P.bWA = (P.tcum4[8] + 255) / 256;
    P.bV  = P.bWA + 512;
    P.bC  = P.bV + 16;
    P.bZ  = P.bC + (NN * 32 + 255) / 256;
    int nblk = P.bZ + (NN / 4 + 255) / 256;
    prep_kernel<<<nblk, 256, 0, stream>>>(P);

    hist_kernel<<<(EE + 255) / 256, 256, 0, stream>>>(dst, counts, EE);
    scan_kernel<<<1, 256, 0, stream>>>(counts, offsets, cursor, NN);
    fill_extra<<<(EE + 255) / 256, 256, 0, stream>>>(src, dst, cursor, edge_feats,
                                                     vbuf, ssrc, extra, EE);

    float* out = (float*)d_out;
    dim3 g128(11, (NN + 63) / 64);
    dim3 g256(21, (NN + 63) / 64);
    int gs128 = NN / 4;   // 4 nodes/block, 1 wave each
    int gs256 = NN / 2;   // 2 nodes/block, 2 waves each

    // ---- layer 1
    gemm_fused<128><<<g128, 256, 0, stream>>>(xb, Wc1, featq, xA, elr, NN);
    gat128<true><<<gs128, 256, 0, stream>>>(featq, elr, extra, ssrc, offsets, xA, xb);
    // ---- layer 2
    gemm_fused<128><<<g128, 256, 0, stream>>>(xb, Wc2, featq, xA, elr, NN);
    gat128<false><<<gs128, 256, 0, stream>>>(featq, elr, nullptr, ssrc, offsets, xA, xb);
    // ---- layer 3
    gemm_fused<128><<<g128, 256, 0, stream>>>(xb, Wc3, featq, xA, elr, NN);
    gat128<false><<<gs128, 256, 0, stream>>>(featq, elr, nullptr, ssrc, offsets, xA, xb);
    // ---- layer 4
    gemm_fused<256><<<g256, 256, 0, stream>>>(xb, Wc4, featq, out, elr, NN);
    gat256<<<gs256, 256, 0, stream>>>(featq, elr, ssrc, offsets, out, out);
}